// Round 16
// baseline (174.904 us; speedup 1.0000x reference)
//
#include <hip/hip_runtime.h>
#include <hip/hip_bf16.h>
#include <math.h>

#define N_TOK 4096

typedef __attribute__((ext_vector_type(8))) short short8;
typedef __attribute__((ext_vector_type(4))) float f32x4;

#define MFMA16(a, b, c) __builtin_amdgcn_mfma_f32_16x16x32_bf16(a, b, c, 0, 0, 0)

__device__ inline unsigned pack_bf16x2(float a, float b) {
    __hip_bfloat16 ha = __float2bfloat16(a), hb = __float2bfloat16(b);
    unsigned short ua = *(unsigned short*)&ha, ub = *(unsigned short*)&hb;
    return (unsigned)ua | ((unsigned)ub << 16);
}

__device__ inline float bf2f(unsigned short u) {
    unsigned v = ((unsigned)u) << 16;
    union { unsigned u; float f; } cv; cv.u = v; return cv.f;
}

// swizzled 16B-chunk slot for row-stride-64B LDS tiles (<=2-way conflicts)
__device__ inline int swz4(int h, int row) { return (h ^ row ^ (row >> 2)) & 3; }

// scale * log2(e), folded into q at projection time
#define SCK 0.25506974748975505f

// ---------------------------------------------------------------------------
// Weight prep: Wo->Wt[tap][o][c] bf16 ; Wq,Wk->Wqk[64][256] ; Wv->Wvb bf16
// ---------------------------------------------------------------------------
__global__ __launch_bounds__(256) void w_prep_kernel(
    const float* __restrict__ Wo, const float* __restrict__ Wq,
    const float* __restrict__ Wk, const float* __restrict__ Wv,
    __hip_bfloat16* __restrict__ Wt, __hip_bfloat16* __restrict__ Wqk,
    __hip_bfloat16* __restrict__ Wvb)
{
    int blk = blockIdx.x, t = threadIdx.x;
    if (blk < 256) {
        const float* src = &Wo[(size_t)(blk * 256 + t) * 9];
#pragma unroll
        for (int tap = 0; tap < 9; ++tap)
            Wt[(size_t)(tap * 256 + blk) * 256 + t] = __float2bfloat16(src[tap]);
    } else if (blk < 260) {
        int r0 = (blk - 256) * 64;
        for (int r = r0; r < r0 + 64; ++r)
            Wvb[r * 256 + t] = __float2bfloat16(Wv[r * 256 + t]);
    } else {
        for (int r = 0; r < 32; ++r) {
            // q rows pre-scaled by SCK (softmax scale * log2e folded in)
            Wqk[r * 256 + t]        = __float2bfloat16(Wq[r * 256 + t] * SCK);
            Wqk[(r + 32) * 256 + t] = __float2bfloat16(Wk[r * 256 + t]);
        }
    }
}

// ---------------------------------------------------------------------------
// Fused QKV projection v2 (r15-proven): block = 32 n, grid B*128 = 512.
// ---------------------------------------------------------------------------
__global__ __launch_bounds__(256) void qkv_kernel(
    const float* __restrict__ x,
    const __hip_bfloat16* __restrict__ Wqk, const __hip_bfloat16* __restrict__ Wvb,
    const float* __restrict__ bq, const float* __restrict__ bk,
    const float* __restrict__ bv,
    __hip_bfloat16* __restrict__ qg, __hip_bfloat16* __restrict__ kg,
    __hip_bfloat16* __restrict__ vg)
{
    __shared__ __hip_bfloat16 tl[32][72];   // [n][c-chunk] pad 8
    int blk = blockIdx.x;
    int b = blk >> 7, n0 = (blk & 127) * 32;
    int t = threadIdx.x, w = t >> 6, lane = t & 63;
    int l15 = lane & 15, l4 = lane >> 4;
    int ns = w & 1, mg = w >> 1;
    int n = n0 + ns * 16 + l15;

    // per-wave A-row base pointers for its 10 m-tiles
    const __hip_bfloat16* wrow[10];
#pragma unroll
    for (int mi = 0; mi < 10; ++mi) {
        int row = mg ? ((6 + mi) * 16 + l15)               // v tiles 6..15
                     : (mi < 4 ? (mi * 16 + l15) : 0);     // qk tiles 0..3
        const __hip_bfloat16* base = mg ? Wvb : (mi < 4 ? Wqk : Wvb);
        if (!mg && mi >= 4) row = (mi - 4) * 16 + l15;     // v tiles 0..5
        wrow[mi] = &base[(size_t)row * 256];
    }

    f32x4 zf = {0.f, 0.f, 0.f, 0.f};
    f32x4 acc[10];
#pragma unroll
    for (int m = 0; m < 10; ++m) acc[m] = zf;

    for (int cc = 0; cc < 256; cc += 64) {
        __syncthreads();
        // ---- stage 64c x 32n transposed -> tl
#pragma unroll
        for (int rep = 0; rep < 2; ++rep) {
            int c = rep * 32 + (t >> 3);
            int n4 = (t & 7) * 4;
            float4 v4 = *(const float4*)&x[((size_t)(b * 256 + cc + c)) * N_TOK + n0 + n4];
            tl[n4 + 0][c] = __float2bfloat16(v4.x);
            tl[n4 + 1][c] = __float2bfloat16(v4.y);
            tl[n4 + 2][c] = __float2bfloat16(v4.z);
            tl[n4 + 3][c] = __float2bfloat16(v4.w);
        }
        __syncthreads();
#pragma unroll
        for (int kk = 0; kk < 2; ++kk) {
            int k0 = cc + kk * 32;
            short8 bfr = *(const short8*)&tl[ns * 16 + l15][kk * 32 + l4 * 8];
#pragma unroll
            for (int mi = 0; mi < 10; ++mi) {
                short8 af = *(const short8*)&wrow[mi][k0 + l4 * 8];
                acc[mi] = MFMA16(af, bfr, acc[mi]);
            }
        }
    }

    if (mg == 0) {
        f32x4 bq0 = *(const f32x4*)&bq[l4 * 4];
        f32x4 bq1 = *(const f32x4*)&bq[16 + l4 * 4];
        f32x4 bk0 = *(const f32x4*)&bk[l4 * 4];
        f32x4 bk1 = *(const f32x4*)&bk[16 + l4 * 4];
        size_t obase = (size_t)(b * N_TOK + n) * 32;
        uint2 u;
        u.x = pack_bf16x2(acc[0][0] + bq0[0] * SCK, acc[0][1] + bq0[1] * SCK);
        u.y = pack_bf16x2(acc[0][2] + bq0[2] * SCK, acc[0][3] + bq0[3] * SCK);
        *(uint2*)&qg[obase + l4 * 4] = u;
        u.x = pack_bf16x2(acc[1][0] + bq1[0] * SCK, acc[1][1] + bq1[1] * SCK);
        u.y = pack_bf16x2(acc[1][2] + bq1[2] * SCK, acc[1][3] + bq1[3] * SCK);
        *(uint2*)&qg[obase + 16 + l4 * 4] = u;
        u.x = pack_bf16x2(acc[2][0] + bk0[0], acc[2][1] + bk0[1]);
        u.y = pack_bf16x2(acc[2][2] + bk0[2], acc[2][3] + bk0[3]);
        *(uint2*)&kg[obase + l4 * 4] = u;
        u.x = pack_bf16x2(acc[3][0] + bk1[0], acc[3][1] + bk1[1]);
        u.y = pack_bf16x2(acc[3][2] + bk1[2], acc[3][3] + bk1[3]);
        *(uint2*)&kg[obase + 16 + l4 * 4] = u;
#pragma unroll
        for (int mi = 4; mi < 10; ++mi) {
            int cb = (mi - 4) * 16 + l4 * 4;
            f32x4 bvv = *(const f32x4*)&bv[cb];
#pragma unroll
            for (int r = 0; r < 4; ++r)
                vg[((size_t)(b * 256 + cb + r)) * N_TOK + n] = __float2bfloat16(acc[mi][r] + bvv[r]);
        }
    } else {
#pragma unroll
        for (int mi = 0; mi < 10; ++mi) {
            int cb = (6 + mi) * 16 + l4 * 4;
            f32x4 bvv = *(const f32x4*)&bv[cb];
#pragma unroll
            for (int r = 0; r < 4; ++r)
                vg[((size_t)(b * 256 + cb + r)) * N_TOK + n] = __float2bfloat16(acc[mi][r] + bvv[r]);
        }
    }
}

// ---------------------------------------------------------------------------
// Flash v9b: kh=3 key-split (1408/1344/1344), wave = 32q x 128c, block =
// 4 waves, grid 768 (3 blocks/CU by LDS=48KB). K via register prefetch,
// V dbuf in LDS, wave-private P. Bare-exp2 softmax.
// ONLY change vs r12: __launch_bounds__(256, 2) — r12's (256,3) made the
// compiler allocate 84 VGPR and demote the K/V prefetch registers, exposing
// full memory latency every iteration. Cap 256 keeps prefetch live (~140).
// ---------------------------------------------------------------------------
__global__ __launch_bounds__(256, 2) void flash_kernel(
    const __hip_bfloat16* __restrict__ qg, const __hip_bfloat16* __restrict__ kg,
    const __hip_bfloat16* __restrict__ vg,
    __hip_bfloat16* __restrict__ ph0, __hip_bfloat16* __restrict__ ph1,
    __hip_bfloat16* __restrict__ ph2, float* __restrict__ Lh)
{
    __shared__ __hip_bfloat16 v_lds[2][128 * 64];  // 32 KB [c][64k]
    __shared__ __hip_bfloat16 p_lds[4][32 * 64];   // 16 KB wave-private [q][64k]

    int blk = blockIdx.x;
    // XCD spread: xcd = blk&7 gets 96 consecutive work units
    int work = (blk & 7) * 96 + (blk >> 3);
    int kh = work >> 8;                     // 0..2 (256 works per kh)
    int rem = work & 255;
    int cs = rem >> 7, b = (rem >> 5) & 3, qgp = rem & 31;
    int koff  = (kh == 0) ? 0 : (kh == 1 ? 1408 : 2752);
    int iters = (kh == 0) ? 22 : 21;
    int t = threadIdx.x, w = t >> 6, lane = t & 63;
    int l15 = lane & 15, l4 = lane >> 4;
    int qw = qgp * 128 + w * 32;

    short8 qf[2];
#pragma unroll
    for (int qs = 0; qs < 2; ++qs)
        qf[qs] = *(const short8*)&qg[((size_t)(b * N_TOK + qw + qs * 16 + l15)) * 32 + l4 * 8];

    f32x4 zf = {0.f, 0.f, 0.f, 0.f};
    f32x4 acc[2][8];
#pragma unroll
    for (int qs = 0; qs < 2; ++qs)
#pragma unroll
        for (int ct = 0; ct < 8; ++ct) acc[qs][ct] = zf;
    float Lr[2] = {0.f, 0.f};

    int vc  = t >> 1;                 // V staging c-row 0..127
    int kb4 = (t & 1) * 4;            // V 16B-chunk base

    const __hip_bfloat16* vrow  = &vg[((size_t)(b * 256 + cs * 128 + vc)) * N_TOK + koff];
    const __hip_bfloat16* kbase = &kg[((size_t)(b * N_TOK + koff)) * 32];

    uint4 vp[4];
    short8 kfr[4], kfn[4];

    // prologue: V(0) -> LDS buf0, K(0) -> regs
#pragma unroll
    for (int j = 0; j < 4; ++j)
        vp[j] = *(const uint4*)&vrow[(kb4 + j) * 8];
#pragma unroll
    for (int kt = 0; kt < 4; ++kt)
        kfr[kt] = *(const short8*)&kbase[(kt * 16 + l15) * 32 + l4 * 8];
#pragma unroll
    for (int j = 0; j < 4; ++j)
        *(uint4*)&v_lds[0][vc * 64 + (((2 * (kb4 + j)) ^ (vc & 14)) << 2)] = vp[j];
    __syncthreads();

    int buf = 0;
    for (int it = 0; it < iters; ++it) {
        int nm0 = it * 64 + 64;
        bool more = (it < iters - 1);
        if (more) {
#pragma unroll
            for (int j = 0; j < 4; ++j)
                vp[j] = *(const uint4*)&vrow[nm0 + (kb4 + j) * 8];
#pragma unroll
            for (int kt = 0; kt < 4; ++kt)
                kfn[kt] = *(const short8*)&kbase[(size_t)(nm0 + kt * 16 + l15) * 32 + l4 * 8];
        }

        // ---- S^T: C[key][q], q = l15, key = kt*16 + l4*4 + r
        f32x4 sf[2][4];
#pragma unroll
        for (int qs = 0; qs < 2; ++qs)
#pragma unroll
            for (int kt = 0; kt < 4; ++kt)
                sf[qs][kt] = MFMA16(kfr[kt], qf[qs], zf);

        // ---- bare exp2 (scale folded into q; shift-free)
#pragma unroll
        for (int qs = 0; qs < 2; ++qs) {
            int prow = qs * 16 + l15;
#pragma unroll
            for (int kt = 0; kt < 4; ++kt) {
                float p0 = exp2f(sf[qs][kt][0]);
                float p1 = exp2f(sf[qs][kt][1]);
                float p2 = exp2f(sf[qs][kt][2]);
                float p3 = exp2f(sf[qs][kt][3]);
                Lr[qs] += (p0 + p1) + (p2 + p3);
                uint2 u;
                u.x = pack_bf16x2(p0, p1);
                u.y = pack_bf16x2(p2, p3);
                *(uint2*)&p_lds[w][prow * 64 + (((kt * 4 + l4) ^ (l15 & 14)) << 2)] = u;
            }
        }

        // ---- PV: A = V^T c-rows (shared across both q-subtiles)
#pragma unroll
        for (int ks = 0; ks < 2; ++ks) {
            short8 pb[2];
#pragma unroll
            for (int qs = 0; qs < 2; ++qs)
                pb[qs] = *(const short8*)&p_lds[w][(qs * 16 + l15) * 64 +
                         (((ks * 8 + l4 * 2) ^ (l15 & 14)) << 2)];
#pragma unroll
            for (int ct = 0; ct < 8; ++ct) {
                int cr = ct * 16 + l15;
                short8 vf = *(const short8*)&v_lds[buf][cr * 64 +
                           (((ks * 8 + l4 * 2) ^ (cr & 14)) << 2)];
                acc[0][ct] = MFMA16(vf, pb[0], acc[0][ct]);
                acc[1][ct] = MFMA16(vf, pb[1], acc[1][ct]);
            }
        }

        // ---- write prefetched V into other buffer, roll K
        if (more) {
#pragma unroll
            for (int j = 0; j < 4; ++j)
                *(uint4*)&v_lds[buf ^ 1][vc * 64 + (((2 * (kb4 + j)) ^ (vc & 14)) << 2)] = vp[j];
#pragma unroll
            for (int kt = 0; kt < 4; ++kt) kfr[kt] = kfn[kt];
            buf ^= 1;
        }
        __syncthreads();
    }

#pragma unroll
    for (int qs = 0; qs < 2; ++qs) {
        float L = Lr[qs];
        L += __shfl_xor(L, 16);
        L += __shfl_xor(L, 32);
        int nq = qw + qs * 16 + l15;
        if (cs == 0 && l4 == 0)
            Lh[kh * 16384 + b * 4096 + nq] = L;
        __hip_bfloat16* pdst = (kh == 0) ? ph0 : (kh == 1 ? ph1 : ph2);
        size_t pix = (size_t)(b * N_TOK + nq);
#pragma unroll
        for (int ct = 0; ct < 8; ++ct) {
            int cl = cs * 128 + ct * 16 + l4 * 4;
            uint2 u;
            u.x = pack_bf16x2(acc[qs][ct][0], acc[qs][ct][1]);
            u.y = pack_bf16x2(acc[qs][ct][2], acc[qs][ct][3]);
            *(uint2*)&pdst[pix * 256 + cl] = u;
        }
    }
}

// ---------------------------------------------------------------------------
// Implicit-GEMM 3x3 conv via MFMA + bias + BN + ReLU + residual.
// Spatial tile 16x8 (grid 512). Staging fuses the 3-way partial-combine
// with inline L sum: att = (ph0 + ph1 + ph2) / (Lh0 + Lh1 + Lh2).
// ---------------------------------------------------------------------------
__global__ __launch_bounds__(256) void conv_mfma_kernel(
    const __hip_bfloat16* __restrict__ ph0, const __hip_bfloat16* __restrict__ ph1,
    const __hip_bfloat16* __restrict__ ph2, const float* __restrict__ Lh,
    const __hip_bfloat16* __restrict__ Wt,
    const float* __restrict__ bo,  const float* __restrict__ gamma,
    const float* __restrict__ beta, const float* __restrict__ mean,
    const float* __restrict__ var, const float* __restrict__ x,
    float* __restrict__ out)
{
    __shared__ __hip_bfloat16 in_lds[180 * 32];     // [10x18 halo][32c] swz
    __shared__ __hip_bfloat16 wt_lds[9 * 64 * 32];  // [tap][o64][32c] swz

    int blk = blockIdx.x;
    int sp = blk & 31, ob = (blk >> 5) & 3, b = blk >> 7;
    int y0 = (sp >> 2) * 8, x0 = (sp & 3) * 16;
    int o0 = ob * 64;
    int t = threadIdx.x;
    int w = t >> 6, lane = t & 63;
    int l15 = lane & 15, l4 = lane >> 4;

    f32x4 zf = {0.f, 0.f, 0.f, 0.f};
    f32x4 acc[4][2];   // [m][ntw]
#pragma unroll
    for (int m = 0; m < 4; ++m)
#pragma unroll
        for (int n = 0; n < 2; ++n) acc[m][n] = zf;

    for (int cc = 0; cc < 256; cc += 32) {
        __syncthreads();
        for (int jj = t; jj < 720; jj += 256) {
            int pix = jj >> 2, h = jj & 3;
            int iy = pix / 18, ix = pix - iy * 18;
            int gy = y0 - 1 + iy, gx = x0 - 1 + ix;
            uint4 val = {0u, 0u, 0u, 0u};
            if (gy >= 0 && gy < 64 && gx >= 0 && gx < 64) {
                int bn = b * 4096 + gy * 64 + gx;
                float inv = 1.f / (Lh[bn] + Lh[16384 + bn] + Lh[32768 + bn]);
                size_t e = (size_t)bn * 256 + cc + h * 8;
                uint4 a  = *(const uint4*)&ph0[e];
                uint4 b4 = *(const uint4*)&ph1[e];
                uint4 c4 = *(const uint4*)&ph2[e];
                const unsigned* ap = (const unsigned*)&a;
                const unsigned* bp = (const unsigned*)&b4;
                const unsigned* cp = (const unsigned*)&c4;
                unsigned* vpn = (unsigned*)&val;
#pragma unroll
                for (int j = 0; j < 4; ++j) {
                    float lo = (bf2f((unsigned short)(ap[j] & 0xffff)) +
                                bf2f((unsigned short)(bp[j] & 0xffff)) +
                                bf2f((unsigned short)(cp[j] & 0xffff))) * inv;
                    float hi = (bf2f((unsigned short)(ap[j] >> 16)) +
                                bf2f((unsigned short)(bp[j] >> 16)) +
                                bf2f((unsigned short)(cp[j] >> 16))) * inv;
                    vpn[j] = pack_bf16x2(lo, hi);
                }
            }
            *(uint4*)&in_lds[pix * 32 + swz4(h, pix) * 8] = val;
        }
        for (int jj = t; jj < 2304; jj += 256) {
            int tap = jj >> 8, rem = jj & 255;
            int o = rem >> 2, h = rem & 3;
            uint4 wv = *(const uint4*)&Wt[((size_t)(tap * 256 + o0 + o)) * 256 + cc + h * 8];
            *(uint4*)&wt_lds[tap * 2048 + o * 32 + swz4(h, o) * 8] = wv;
        }
        __syncthreads();

#pragma unroll
        for (int ky = 0; ky < 3; ++ky) {
#pragma unroll
            for (int kx = 0; kx < 3; ++kx) {
                int tap = ky * 3 + kx;
                short8 af[4];
#pragma unroll
                for (int m = 0; m < 4; ++m) {
                    int orow = m * 16 + l15;
                    af[m] = *(const short8*)&wt_lds[tap * 2048 + orow * 32 + swz4(l4, orow) * 8];
                }
#pragma unroll
                for (int ntw = 0; ntw < 2; ++ntw) {
                    int yy = w * 2 + ntw;
                    int p = (yy + ky) * 18 + kx + l15;
                    short8 bfr = *(const short8*)&in_lds[p * 32 + swz4(l4, p) * 8];
#pragma unroll
                    for (int m = 0; m < 4; ++m)
                        acc[m][ntw] = MFMA16(af[m], bfr, acc[m][ntw]);
                }
            }
        }
    }

#pragma unroll
    for (int m = 0; m < 4; ++m) {
#pragma unroll
        for (int r = 0; r < 4; ++r) {
            int oc = o0 + m * 16 + l4 * 4 + r;
            float inv = gamma[oc] * rsqrtf(var[oc] + 1e-5f);
            float sh  = (bo[oc] - mean[oc]) * inv + beta[oc];
#pragma unroll
            for (int ntw = 0; ntw < 2; ++ntw) {
                int gy = y0 + w * 2 + ntw, gx = x0 + l15;
                size_t idx = (size_t)(b * 256 + oc) * 4096 + (size_t)gy * 64 + gx;
                float yv = acc[m][ntw][r] * inv + sh;
                yv = fmaxf(yv, 0.f);
                out[idx] = yv + x[idx];
            }
        }
    }
}

// ---------------------------------------------------------------------------
extern "C" void kernel_launch(void* const* d_in, const int* in_sizes, int n_in,
                              void* d_out, int out_size, void* d_ws, size_t ws_size,
                              hipStream_t stream)
{
    const float* x  = (const float*)d_in[0];
    const float* Wq = (const float*)d_in[1];
    const float* bq = (const float*)d_in[2];
    const float* Wk = (const float*)d_in[3];
    const float* bk = (const float*)d_in[4];
    const float* Wv = (const float*)d_in[5];
    const float* bv = (const float*)d_in[6];
    const float* Wo = (const float*)d_in[7];
    const float* bo = (const float*)d_in[8];
    const float* gm = (const float*)d_in[9];
    const float* bt = (const float*)d_in[10];
    const float* mn = (const float*)d_in[11];
    const float* vr = (const float*)d_in[12];
    float* out = (float*)d_out;

    char* wsb = (char*)d_ws;
    __hip_bfloat16* qg  = (__hip_bfloat16*)(wsb);                      // 1 MB
    __hip_bfloat16* kg  = (__hip_bfloat16*)(wsb + (1u  << 20));        // 1 MB
    __hip_bfloat16* vg  = (__hip_bfloat16*)(wsb + (2u  << 20));        // 8 MB
    __hip_bfloat16* ph1 = (__hip_bfloat16*)(wsb + (10u << 20));        // 8 MB
    __hip_bfloat16* Wt  = (__hip_bfloat16*)(wsb + (18u << 20));        // 1.2 MB
    __hip_bfloat16* ph0 = (__hip_bfloat16*)(wsb + (20u << 20));        // 8 MB
    __hip_bfloat16* Wqk = (__hip_bfloat16*)(wsb + (28u << 20));        // 32 KB
    __hip_bfloat16* Wvb = (__hip_bfloat16*)(wsb + (28u << 20) + 65536);// 128 KB
    float*          Lh  = (float*)(wsb + (28u << 20) + 262144);        // 192 KB
    __hip_bfloat16* ph2 = (__hip_bfloat16*)(wsb + (29u << 20));        // 8 MB -> 37 MB

    w_prep_kernel  <<<261,  256, 0, stream>>>(Wo, Wq, Wk, Wv, Wt, Wqk, Wvb);
    qkv_kernel     <<<512,  256, 0, stream>>>(x, Wqk, Wvb, bq, bk, bv, qg, kg, vg);
    flash_kernel   <<<768,  256, 0, stream>>>(qg, kg, vg, ph0, ph1, ph2, Lh);
    conv_mfma_kernel<<<512, 256, 0, stream>>>(ph0, ph1, ph2, Lh, Wt, bo, gm, bt, mn, vr, x, out);
}

// Round 17
// 144.866 us; speedup vs baseline: 1.2074x; 1.2074x over previous
//
#include <hip/hip_runtime.h>
#include <hip/hip_bf16.h>
#include <math.h>

#define N_TOK 4096

typedef __attribute__((ext_vector_type(8))) short short8;
typedef __attribute__((ext_vector_type(4))) float f32x4;

#define MFMA16(a, b, c) __builtin_amdgcn_mfma_f32_16x16x32_bf16(a, b, c, 0, 0, 0)

__device__ inline unsigned pack_bf16x2(float a, float b) {
    __hip_bfloat16 ha = __float2bfloat16(a), hb = __float2bfloat16(b);
    unsigned short ua = *(unsigned short*)&ha, ub = *(unsigned short*)&hb;
    return (unsigned)ua | ((unsigned)ub << 16);
}

__device__ inline float bf2f(unsigned short u) {
    unsigned v = ((unsigned)u) << 16;
    union { unsigned u; float f; } cv; cv.u = v; return cv.f;
}

// swizzled 16B-chunk slot for row-stride-64B LDS tiles (<=2-way conflicts)
__device__ inline int swz4(int h, int row) { return (h ^ row ^ (row >> 2)) & 3; }

// scale * log2(e), folded into q at projection time
#define SCK 0.25506974748975505f

// ---------------------------------------------------------------------------
// Weight prep: Wo->Wt[tap][o][c] bf16 ; Wq,Wk->Wqk[64][256] ; Wv->Wvb bf16
// ---------------------------------------------------------------------------
__global__ __launch_bounds__(256) void w_prep_kernel(
    const float* __restrict__ Wo, const float* __restrict__ Wq,
    const float* __restrict__ Wk, const float* __restrict__ Wv,
    __hip_bfloat16* __restrict__ Wt, __hip_bfloat16* __restrict__ Wqk,
    __hip_bfloat16* __restrict__ Wvb)
{
    int blk = blockIdx.x, t = threadIdx.x;
    if (blk < 256) {
        const float* src = &Wo[(size_t)(blk * 256 + t) * 9];
#pragma unroll
        for (int tap = 0; tap < 9; ++tap)
            Wt[(size_t)(tap * 256 + blk) * 256 + t] = __float2bfloat16(src[tap]);
    } else if (blk < 260) {
        int r0 = (blk - 256) * 64;
        for (int r = r0; r < r0 + 64; ++r)
            Wvb[r * 256 + t] = __float2bfloat16(Wv[r * 256 + t]);
    } else {
        for (int r = 0; r < 32; ++r) {
            // q rows pre-scaled by SCK (softmax scale * log2e folded in)
            Wqk[r * 256 + t]        = __float2bfloat16(Wq[r * 256 + t] * SCK);
            Wqk[(r + 32) * 256 + t] = __float2bfloat16(Wk[r * 256 + t]);
        }
    }
}

// ---------------------------------------------------------------------------
// Fused QKV projection v2 (r15-proven): block = 32 n, grid B*128 = 512.
// ---------------------------------------------------------------------------
__global__ __launch_bounds__(256) void qkv_kernel(
    const float* __restrict__ x,
    const __hip_bfloat16* __restrict__ Wqk, const __hip_bfloat16* __restrict__ Wvb,
    const float* __restrict__ bq, const float* __restrict__ bk,
    const float* __restrict__ bv,
    __hip_bfloat16* __restrict__ qg, __hip_bfloat16* __restrict__ kg,
    __hip_bfloat16* __restrict__ vg)
{
    __shared__ __hip_bfloat16 tl[32][72];   // [n][c-chunk] pad 8
    int blk = blockIdx.x;
    int b = blk >> 7, n0 = (blk & 127) * 32;
    int t = threadIdx.x, w = t >> 6, lane = t & 63;
    int l15 = lane & 15, l4 = lane >> 4;
    int ns = w & 1, mg = w >> 1;
    int n = n0 + ns * 16 + l15;

    // per-wave A-row base pointers for its 10 m-tiles
    const __hip_bfloat16* wrow[10];
#pragma unroll
    for (int mi = 0; mi < 10; ++mi) {
        int row = mg ? ((6 + mi) * 16 + l15)               // v tiles 6..15
                     : (mi < 4 ? (mi * 16 + l15) : 0);     // qk tiles 0..3
        const __hip_bfloat16* base = mg ? Wvb : (mi < 4 ? Wqk : Wvb);
        if (!mg && mi >= 4) row = (mi - 4) * 16 + l15;     // v tiles 0..5
        wrow[mi] = &base[(size_t)row * 256];
    }

    f32x4 zf = {0.f, 0.f, 0.f, 0.f};
    f32x4 acc[10];
#pragma unroll
    for (int m = 0; m < 10; ++m) acc[m] = zf;

    for (int cc = 0; cc < 256; cc += 64) {
        __syncthreads();
        // ---- stage 64c x 32n transposed -> tl
#pragma unroll
        for (int rep = 0; rep < 2; ++rep) {
            int c = rep * 32 + (t >> 3);
            int n4 = (t & 7) * 4;
            float4 v4 = *(const float4*)&x[((size_t)(b * 256 + cc + c)) * N_TOK + n0 + n4];
            tl[n4 + 0][c] = __float2bfloat16(v4.x);
            tl[n4 + 1][c] = __float2bfloat16(v4.y);
            tl[n4 + 2][c] = __float2bfloat16(v4.z);
            tl[n4 + 3][c] = __float2bfloat16(v4.w);
        }
        __syncthreads();
#pragma unroll
        for (int kk = 0; kk < 2; ++kk) {
            int k0 = cc + kk * 32;
            short8 bfr = *(const short8*)&tl[ns * 16 + l15][kk * 32 + l4 * 8];
#pragma unroll
            for (int mi = 0; mi < 10; ++mi) {
                short8 af = *(const short8*)&wrow[mi][k0 + l4 * 8];
                acc[mi] = MFMA16(af, bfr, acc[mi]);
            }
        }
    }

    if (mg == 0) {
        f32x4 bq0 = *(const f32x4*)&bq[l4 * 4];
        f32x4 bq1 = *(const f32x4*)&bq[16 + l4 * 4];
        f32x4 bk0 = *(const f32x4*)&bk[l4 * 4];
        f32x4 bk1 = *(const f32x4*)&bk[16 + l4 * 4];
        size_t obase = (size_t)(b * N_TOK + n) * 32;
        uint2 u;
        u.x = pack_bf16x2(acc[0][0] + bq0[0] * SCK, acc[0][1] + bq0[1] * SCK);
        u.y = pack_bf16x2(acc[0][2] + bq0[2] * SCK, acc[0][3] + bq0[3] * SCK);
        *(uint2*)&qg[obase + l4 * 4] = u;
        u.x = pack_bf16x2(acc[1][0] + bq1[0] * SCK, acc[1][1] + bq1[1] * SCK);
        u.y = pack_bf16x2(acc[1][2] + bq1[2] * SCK, acc[1][3] + bq1[3] * SCK);
        *(uint2*)&qg[obase + 16 + l4 * 4] = u;
        u.x = pack_bf16x2(acc[2][0] + bk0[0], acc[2][1] + bk0[1]);
        u.y = pack_bf16x2(acc[2][2] + bk0[2], acc[2][3] + bk0[3]);
        *(uint2*)&kg[obase + l4 * 4] = u;
        u.x = pack_bf16x2(acc[3][0] + bk1[0], acc[3][1] + bk1[1]);
        u.y = pack_bf16x2(acc[3][2] + bk1[2], acc[3][3] + bk1[3]);
        *(uint2*)&kg[obase + 16 + l4 * 4] = u;
#pragma unroll
        for (int mi = 4; mi < 10; ++mi) {
            int cb = (mi - 4) * 16 + l4 * 4;
            f32x4 bvv = *(const f32x4*)&bv[cb];
#pragma unroll
            for (int r = 0; r < 4; ++r)
                vg[((size_t)(b * 256 + cb + r)) * N_TOK + n] = __float2bfloat16(acc[mi][r] + bvv[r]);
        }
    } else {
#pragma unroll
        for (int mi = 0; mi < 10; ++mi) {
            int cb = (6 + mi) * 16 + l4 * 4;
            f32x4 bvv = *(const f32x4*)&bv[cb];
#pragma unroll
            for (int r = 0; r < 4; ++r)
                vg[((size_t)(b * 256 + cb + r)) * N_TOK + n] = __float2bfloat16(acc[mi][r] + bvv[r]);
        }
    }
}

// ---------------------------------------------------------------------------
// Flash v8 (r13-proven, byte-identical): kh=2 key-split, wave = 32q x 128c,
// block = 4 waves, grid = 512 (2 blocks/CU). K staged in LDS (swz4), V dbuf,
// wave-private P. Bare-exp2 softmax, unnormalized partials + L.
// FROZEN: kh=3 (r12,r16) and unroll-2 (r14) all regressed. Do not perturb.
// ---------------------------------------------------------------------------
__global__ __launch_bounds__(256, 2) void flash_kernel(
    const __hip_bfloat16* __restrict__ qg, const __hip_bfloat16* __restrict__ kg,
    const __hip_bfloat16* __restrict__ vg,
    __hip_bfloat16* __restrict__ ph0, __hip_bfloat16* __restrict__ ph1,
    float* __restrict__ Lh)
{
    __shared__ __hip_bfloat16 v_lds[2][128 * 64];  // 32 KB [c][64k]
    __shared__ __hip_bfloat16 k_lds[2][64 * 32];   // 8 KB [key][32d]
    __shared__ __hip_bfloat16 p_lds[4][32 * 64];   // 16 KB wave-private [q][64k]

    int blk = blockIdx.x;
    int work = (blk & 7) * 64 + (blk >> 3);
    int g = work >> 6;
    int kh = g >> 2, cs = (g >> 1) & 1, bl = g & 1;
    int rem = work & 63;
    int b = ((rem >> 5) << 1) | bl;
    int qgp = rem & 31;
    int t = threadIdx.x, w = t >> 6, lane = t & 63;
    int l15 = lane & 15, l4 = lane >> 4;
    int qw = qgp * 128 + w * 32;

    short8 qf[2];
#pragma unroll
    for (int qs = 0; qs < 2; ++qs)
        qf[qs] = *(const short8*)&qg[((size_t)(b * N_TOK + qw + qs * 16 + l15)) * 32 + l4 * 8];

    f32x4 zf = {0.f, 0.f, 0.f, 0.f};
    f32x4 acc[2][8];
#pragma unroll
    for (int qs = 0; qs < 2; ++qs)
#pragma unroll
        for (int ct = 0; ct < 8; ++ct) acc[qs][ct] = zf;
    float Lr[2] = {0.f, 0.f};

    int vc  = t >> 1;
    int kb4 = (t & 1) * 4;
    int kr  = t >> 2;
    int kch = t & 3;

    const __hip_bfloat16* vrow  = &vg[((size_t)(b * 256 + cs * 128 + vc)) * N_TOK + kh * 2048];
    const __hip_bfloat16* kbase = &kg[((size_t)(b * N_TOK + kh * 2048)) * 32];

    uint4 vp[4], kp;

#pragma unroll
    for (int j = 0; j < 4; ++j)
        vp[j] = *(const uint4*)&vrow[(kb4 + j) * 8];
    kp = *(const uint4*)&kbase[kr * 32 + kch * 8];
#pragma unroll
    for (int j = 0; j < 4; ++j)
        *(uint4*)&v_lds[0][vc * 64 + (((2 * (kb4 + j)) ^ (vc & 14)) << 2)] = vp[j];
    *(uint4*)&k_lds[0][kr * 32 + swz4(kch, kr) * 8] = kp;
    __syncthreads();

    int buf = 0;
    for (int it = 0; it < 32; ++it) {
        int nm0 = it * 64 + 64;
        bool more = (it < 31);
        if (more) {
#pragma unroll
            for (int j = 0; j < 4; ++j)
                vp[j] = *(const uint4*)&vrow[nm0 + (kb4 + j) * 8];
            kp = *(const uint4*)&kbase[(size_t)(nm0 + kr) * 32 + kch * 8];
        }

        short8 kf[4];
#pragma unroll
        for (int kt = 0; kt < 4; ++kt) {
            int row = kt * 16 + l15;
            kf[kt] = *(const short8*)&k_lds[buf][row * 32 + swz4(l4, row) * 8];
        }
        f32x4 sf[2][4];
#pragma unroll
        for (int qs = 0; qs < 2; ++qs)
#pragma unroll
            for (int kt = 0; kt < 4; ++kt)
                sf[qs][kt] = MFMA16(kf[kt], qf[qs], zf);

        // ---- bare exp2 (scale folded into q; no shift needed)
#pragma unroll
        for (int qs = 0; qs < 2; ++qs) {
            int prow = qs * 16 + l15;
#pragma unroll
            for (int kt = 0; kt < 4; ++kt) {
                float p0 = exp2f(sf[qs][kt][0]);
                float p1 = exp2f(sf[qs][kt][1]);
                float p2 = exp2f(sf[qs][kt][2]);
                float p3 = exp2f(sf[qs][kt][3]);
                Lr[qs] += (p0 + p1) + (p2 + p3);
                uint2 u;
                u.x = pack_bf16x2(p0, p1);
                u.y = pack_bf16x2(p2, p3);
                *(uint2*)&p_lds[w][prow * 64 + (((kt * 4 + l4) ^ (l15 & 14)) << 2)] = u;
            }
        }

#pragma unroll
        for (int ks = 0; ks < 2; ++ks) {
            short8 pb[2];
#pragma unroll
            for (int qs = 0; qs < 2; ++qs)
                pb[qs] = *(const short8*)&p_lds[w][(qs * 16 + l15) * 64 +
                         (((ks * 8 + l4 * 2) ^ (l15 & 14)) << 2)];
#pragma unroll
            for (int ct = 0; ct < 8; ++ct) {
                int cr = ct * 16 + l15;
                short8 vf = *(const short8*)&v_lds[buf][cr * 64 +
                           (((ks * 8 + l4 * 2) ^ (cr & 14)) << 2)];
                acc[0][ct] = MFMA16(vf, pb[0], acc[0][ct]);
                acc[1][ct] = MFMA16(vf, pb[1], acc[1][ct]);
            }
        }

        if (more) {
#pragma unroll
            for (int j = 0; j < 4; ++j)
                *(uint4*)&v_lds[buf ^ 1][vc * 64 + (((2 * (kb4 + j)) ^ (vc & 14)) << 2)] = vp[j];
            *(uint4*)&k_lds[buf ^ 1][kr * 32 + swz4(kch, kr) * 8] = kp;
            buf ^= 1;
        }
        __syncthreads();
    }

#pragma unroll
    for (int qs = 0; qs < 2; ++qs) {
        float L = Lr[qs];
        L += __shfl_xor(L, 16);
        L += __shfl_xor(L, 32);
        int nq = qw + qs * 16 + l15;
        if (cs == 0 && l4 == 0)
            Lh[kh * 16384 + b * 4096 + nq] = L;
        __hip_bfloat16* pdst = kh ? ph1 : ph0;
        size_t pix = (size_t)(b * N_TOK + nq);
#pragma unroll
        for (int ct = 0; ct < 8; ++ct) {
            int cl = cs * 128 + ct * 16 + l4 * 4;
            uint2 u;
            u.x = pack_bf16x2(acc[qs][ct][0], acc[qs][ct][1]);
            u.y = pack_bf16x2(acc[qs][ct][2], acc[qs][ct][3]);
            *(uint2*)&pdst[pix * 256 + cl] = u;
        }
    }
}

// ---------------------------------------------------------------------------
// Implicit-GEMM 3x3 conv via MFMA + bias + BN + ReLU + residual.
// v3: o-split 64 -> 32 (grid 1024 = 4 blocks/CU = 4 waves/SIMD; LDS 30KB).
// Spatial tile 16x8. Staging fuses partial-combine + inline L sum.
// ---------------------------------------------------------------------------
__global__ __launch_bounds__(256) void conv_mfma_kernel(
    const __hip_bfloat16* __restrict__ ph0, const __hip_bfloat16* __restrict__ ph1,
    const float* __restrict__ Lh, const __hip_bfloat16* __restrict__ Wt,
    const float* __restrict__ bo,  const float* __restrict__ gamma,
    const float* __restrict__ beta, const float* __restrict__ mean,
    const float* __restrict__ var, const float* __restrict__ x,
    float* __restrict__ out)
{
    __shared__ __hip_bfloat16 in_lds[180 * 32];     // [10x18 halo][32c] swz
    __shared__ __hip_bfloat16 wt_lds[9 * 32 * 32];  // [tap][o32][32c] swz

    int blk = blockIdx.x;
    int sp = blk & 31, ob = (blk >> 5) & 7, b = blk >> 8;
    int y0 = (sp >> 2) * 8, x0 = (sp & 3) * 16;
    int o0 = ob * 32;
    int t = threadIdx.x;
    int w = t >> 6, lane = t & 63;
    int l15 = lane & 15, l4 = lane >> 4;

    f32x4 zf = {0.f, 0.f, 0.f, 0.f};
    f32x4 acc[2][2];   // [m][ntw]
#pragma unroll
    for (int m = 0; m < 2; ++m)
#pragma unroll
        for (int n = 0; n < 2; ++n) acc[m][n] = zf;

    for (int cc = 0; cc < 256; cc += 32) {
        __syncthreads();
        for (int jj = t; jj < 720; jj += 256) {
            int pix = jj >> 2, h = jj & 3;
            int iy = pix / 18, ix = pix - iy * 18;
            int gy = y0 - 1 + iy, gx = x0 - 1 + ix;
            uint4 val = {0u, 0u, 0u, 0u};
            if (gy >= 0 && gy < 64 && gx >= 0 && gx < 64) {
                int bn = b * 4096 + gy * 64 + gx;
                float inv = 1.f / (Lh[bn] + Lh[16384 + bn]);
                size_t e = (size_t)bn * 256 + cc + h * 8;
                uint4 a  = *(const uint4*)&ph0[e];
                uint4 b4 = *(const uint4*)&ph1[e];
                const unsigned* ap = (const unsigned*)&a;
                const unsigned* bp = (const unsigned*)&b4;
                unsigned* vpn = (unsigned*)&val;
#pragma unroll
                for (int j = 0; j < 4; ++j) {
                    float lo = (bf2f((unsigned short)(ap[j] & 0xffff)) +
                                bf2f((unsigned short)(bp[j] & 0xffff))) * inv;
                    float hi = (bf2f((unsigned short)(ap[j] >> 16)) +
                                bf2f((unsigned short)(bp[j] >> 16))) * inv;
                    vpn[j] = pack_bf16x2(lo, hi);
                }
            }
            *(uint4*)&in_lds[pix * 32 + swz4(h, pix) * 8] = val;
        }
        for (int jj = t; jj < 1152; jj += 256) {
            int tap = jj >> 7, rem = jj & 127;
            int o = rem >> 2, h = rem & 3;
            uint4 wv = *(const uint4*)&Wt[((size_t)(tap * 256 + o0 + o)) * 256 + cc + h * 8];
            *(uint4*)&wt_lds[tap * 1024 + o * 32 + swz4(h, o) * 8] = wv;
        }
        __syncthreads();

#pragma unroll
        for (int ky = 0; ky < 3; ++ky) {
#pragma unroll
            for (int kx = 0; kx < 3; ++kx) {
                int tap = ky * 3 + kx;
                short8 af[2];
#pragma unroll
                for (int m = 0; m < 2; ++m) {
                    int orow = m * 16 + l15;
                    af[m] = *(const short8*)&wt_lds[tap * 1024 + orow * 32 + swz4(l4, orow) * 8];
                }
#pragma unroll
                for (int ntw = 0; ntw < 2; ++ntw) {
                    int yy = w * 2 + ntw;
                    int p = (yy + ky) * 18 + kx + l15;
                    short8 bfr = *(const short8*)&in_lds[p * 32 + swz4(l4, p) * 8];
#pragma unroll
                    for (int m = 0; m < 2; ++m)
                        acc[m][ntw] = MFMA16(af[m], bfr, acc[m][ntw]);
                }
            }
        }
    }

#pragma unroll
    for (int m = 0; m < 2; ++m) {
#pragma unroll
        for (int r = 0; r < 4; ++r) {
            int oc = o0 + m * 16 + l4 * 4 + r;
            float inv = gamma[oc] * rsqrtf(var[oc] + 1e-5f);
            float sh  = (bo[oc] - mean[oc]) * inv + beta[oc];
#pragma unroll
            for (int ntw = 0; ntw < 2; ++ntw) {
                int gy = y0 + w * 2 + ntw, gx = x0 + l15;
                size_t idx = (size_t)(b * 256 + oc) * 4096 + (size_t)gy * 64 + gx;
                float yv = acc[m][ntw][r] * inv + sh;
                yv = fmaxf(yv, 0.f);
                out[idx] = yv + x[idx];
            }
        }
    }
}

// ---------------------------------------------------------------------------
extern "C" void kernel_launch(void* const* d_in, const int* in_sizes, int n_in,
                              void* d_out, int out_size, void* d_ws, size_t ws_size,
                              hipStream_t stream)
{
    const float* x  = (const float*)d_in[0];
    const float* Wq = (const float*)d_in[1];
    const float* bq = (const float*)d_in[2];
    const float* Wk = (const float*)d_in[3];
    const float* bk = (const float*)d_in[4];
    const float* Wv = (const float*)d_in[5];
    const float* bv = (const float*)d_in[6];
    const float* Wo = (const float*)d_in[7];
    const float* bo = (const float*)d_in[8];
    const float* gm = (const float*)d_in[9];
    const float* bt = (const float*)d_in[10];
    const float* mn = (const float*)d_in[11];
    const float* vr = (const float*)d_in[12];
    float* out = (float*)d_out;

    char* wsb = (char*)d_ws;
    __hip_bfloat16* qg  = (__hip_bfloat16*)(wsb);                      // 1 MB
    __hip_bfloat16* kg  = (__hip_bfloat16*)(wsb + (1u  << 20));        // 1 MB
    __hip_bfloat16* vg  = (__hip_bfloat16*)(wsb + (2u  << 20));        // 8 MB
    __hip_bfloat16* ph1 = (__hip_bfloat16*)(wsb + (10u << 20));        // 8 MB
    __hip_bfloat16* Wt  = (__hip_bfloat16*)(wsb + (18u << 20));        // 1.2 MB
    __hip_bfloat16* ph0 = (__hip_bfloat16*)(wsb + (20u << 20));        // 8 MB
    __hip_bfloat16* Wqk = (__hip_bfloat16*)(wsb + (28u << 20));        // 32 KB
    __hip_bfloat16* Wvb = (__hip_bfloat16*)(wsb + (28u << 20) + 65536);// 128 KB
    float*          Lh  = (float*)(wsb + (28u << 20) + 262144);        // 128 KB

    w_prep_kernel  <<<261,  256, 0, stream>>>(Wo, Wq, Wk, Wv, Wt, Wqk, Wvb);
    qkv_kernel     <<<512,  256, 0, stream>>>(x, Wqk, Wvb, bq, bk, bv, qg, kg, vg);
    flash_kernel   <<<512,  256, 0, stream>>>(qg, kg, vg, ph0, ph1, Lh);
    conv_mfma_kernel<<<1024, 256, 0, stream>>>(ph0, ph1, Lh, Wt, bo, gm, bt, mn, vr, x, out);
}

// Round 18
// 141.565 us; speedup vs baseline: 1.2355x; 1.0233x over previous
//
#include <hip/hip_runtime.h>
#include <hip/hip_bf16.h>
#include <math.h>

#define N_TOK 4096

typedef __attribute__((ext_vector_type(8))) short short8;
typedef __attribute__((ext_vector_type(4))) float f32x4;

#define MFMA16(a, b, c) __builtin_amdgcn_mfma_f32_16x16x32_bf16(a, b, c, 0, 0, 0)

__device__ inline unsigned pack_bf16x2(float a, float b) {
    __hip_bfloat16 ha = __float2bfloat16(a), hb = __float2bfloat16(b);
    unsigned short ua = *(unsigned short*)&ha, ub = *(unsigned short*)&hb;
    return (unsigned)ua | ((unsigned)ub << 16);
}

__device__ inline float bf2f(unsigned short u) {
    unsigned v = ((unsigned)u) << 16;
    union { unsigned u; float f; } cv; cv.u = v; return cv.f;
}

// swizzled 16B-chunk slot for row-stride-64B LDS tiles (<=2-way conflicts)
__device__ inline int swz4(int h, int row) { return (h ^ row ^ (row >> 2)) & 3; }

// scale * log2(e), folded into q at projection time
#define SCK 0.25506974748975505f

// ---------------------------------------------------------------------------
// Weight prep: Wo->Wt[tap][o][c] bf16 ; Wq,Wk->Wqk[64][256] ; Wv->Wvb bf16
// ---------------------------------------------------------------------------
__global__ __launch_bounds__(256) void w_prep_kernel(
    const float* __restrict__ Wo, const float* __restrict__ Wq,
    const float* __restrict__ Wk, const float* __restrict__ Wv,
    __hip_bfloat16* __restrict__ Wt, __hip_bfloat16* __restrict__ Wqk,
    __hip_bfloat16* __restrict__ Wvb)
{
    int blk = blockIdx.x, t = threadIdx.x;
    if (blk < 256) {
        const float* src = &Wo[(size_t)(blk * 256 + t) * 9];
#pragma unroll
        for (int tap = 0; tap < 9; ++tap)
            Wt[(size_t)(tap * 256 + blk) * 256 + t] = __float2bfloat16(src[tap]);
    } else if (blk < 260) {
        int r0 = (blk - 256) * 64;
        for (int r = r0; r < r0 + 64; ++r)
            Wvb[r * 256 + t] = __float2bfloat16(Wv[r * 256 + t]);
    } else {
        for (int r = 0; r < 32; ++r) {
            // q rows pre-scaled by SCK (softmax scale * log2e folded in)
            Wqk[r * 256 + t]        = __float2bfloat16(Wq[r * 256 + t] * SCK);
            Wqk[(r + 32) * 256 + t] = __float2bfloat16(Wk[r * 256 + t]);
        }
    }
}

// ---------------------------------------------------------------------------
// Fused QKV projection v2 (r15-proven): block = 32 n, grid B*128 = 512.
// ---------------------------------------------------------------------------
__global__ __launch_bounds__(256) void qkv_kernel(
    const float* __restrict__ x,
    const __hip_bfloat16* __restrict__ Wqk, const __hip_bfloat16* __restrict__ Wvb,
    const float* __restrict__ bq, const float* __restrict__ bk,
    const float* __restrict__ bv,
    __hip_bfloat16* __restrict__ qg, __hip_bfloat16* __restrict__ kg,
    __hip_bfloat16* __restrict__ vg)
{
    __shared__ __hip_bfloat16 tl[32][72];   // [n][c-chunk] pad 8
    int blk = blockIdx.x;
    int b = blk >> 7, n0 = (blk & 127) * 32;
    int t = threadIdx.x, w = t >> 6, lane = t & 63;
    int l15 = lane & 15, l4 = lane >> 4;
    int ns = w & 1, mg = w >> 1;
    int n = n0 + ns * 16 + l15;

    // per-wave A-row base pointers for its 10 m-tiles
    const __hip_bfloat16* wrow[10];
#pragma unroll
    for (int mi = 0; mi < 10; ++mi) {
        int row = mg ? ((6 + mi) * 16 + l15)               // v tiles 6..15
                     : (mi < 4 ? (mi * 16 + l15) : 0);     // qk tiles 0..3
        const __hip_bfloat16* base = mg ? Wvb : (mi < 4 ? Wqk : Wvb);
        if (!mg && mi >= 4) row = (mi - 4) * 16 + l15;     // v tiles 0..5
        wrow[mi] = &base[(size_t)row * 256];
    }

    f32x4 zf = {0.f, 0.f, 0.f, 0.f};
    f32x4 acc[10];
#pragma unroll
    for (int m = 0; m < 10; ++m) acc[m] = zf;

    for (int cc = 0; cc < 256; cc += 64) {
        __syncthreads();
        // ---- stage 64c x 32n transposed -> tl
#pragma unroll
        for (int rep = 0; rep < 2; ++rep) {
            int c = rep * 32 + (t >> 3);
            int n4 = (t & 7) * 4;
            float4 v4 = *(const float4*)&x[((size_t)(b * 256 + cc + c)) * N_TOK + n0 + n4];
            tl[n4 + 0][c] = __float2bfloat16(v4.x);
            tl[n4 + 1][c] = __float2bfloat16(v4.y);
            tl[n4 + 2][c] = __float2bfloat16(v4.z);
            tl[n4 + 3][c] = __float2bfloat16(v4.w);
        }
        __syncthreads();
#pragma unroll
        for (int kk = 0; kk < 2; ++kk) {
            int k0 = cc + kk * 32;
            short8 bfr = *(const short8*)&tl[ns * 16 + l15][kk * 32 + l4 * 8];
#pragma unroll
            for (int mi = 0; mi < 10; ++mi) {
                short8 af = *(const short8*)&wrow[mi][k0 + l4 * 8];
                acc[mi] = MFMA16(af, bfr, acc[mi]);
            }
        }
    }

    if (mg == 0) {
        f32x4 bq0 = *(const f32x4*)&bq[l4 * 4];
        f32x4 bq1 = *(const f32x4*)&bq[16 + l4 * 4];
        f32x4 bk0 = *(const f32x4*)&bk[l4 * 4];
        f32x4 bk1 = *(const f32x4*)&bk[16 + l4 * 4];
        size_t obase = (size_t)(b * N_TOK + n) * 32;
        uint2 u;
        u.x = pack_bf16x2(acc[0][0] + bq0[0] * SCK, acc[0][1] + bq0[1] * SCK);
        u.y = pack_bf16x2(acc[0][2] + bq0[2] * SCK, acc[0][3] + bq0[3] * SCK);
        *(uint2*)&qg[obase + l4 * 4] = u;
        u.x = pack_bf16x2(acc[1][0] + bq1[0] * SCK, acc[1][1] + bq1[1] * SCK);
        u.y = pack_bf16x2(acc[1][2] + bq1[2] * SCK, acc[1][3] + bq1[3] * SCK);
        *(uint2*)&qg[obase + 16 + l4 * 4] = u;
        u.x = pack_bf16x2(acc[2][0] + bk0[0], acc[2][1] + bk0[1]);
        u.y = pack_bf16x2(acc[2][2] + bk0[2], acc[2][3] + bk0[3]);
        *(uint2*)&kg[obase + l4 * 4] = u;
        u.x = pack_bf16x2(acc[3][0] + bk1[0], acc[3][1] + bk1[1]);
        u.y = pack_bf16x2(acc[3][2] + bk1[2], acc[3][3] + bk1[3]);
        *(uint2*)&kg[obase + 16 + l4 * 4] = u;
#pragma unroll
        for (int mi = 4; mi < 10; ++mi) {
            int cb = (mi - 4) * 16 + l4 * 4;
            f32x4 bvv = *(const f32x4*)&bv[cb];
#pragma unroll
            for (int r = 0; r < 4; ++r)
                vg[((size_t)(b * 256 + cb + r)) * N_TOK + n] = __float2bfloat16(acc[mi][r] + bvv[r]);
        }
    } else {
#pragma unroll
        for (int mi = 0; mi < 10; ++mi) {
            int cb = (6 + mi) * 16 + l4 * 4;
            f32x4 bvv = *(const f32x4*)&bv[cb];
#pragma unroll
            for (int r = 0; r < 4; ++r)
                vg[((size_t)(b * 256 + cb + r)) * N_TOK + n] = __float2bfloat16(acc[mi][r] + bvv[r]);
        }
    }
}

// ---------------------------------------------------------------------------
// Flash v8 (r13-proven, byte-identical): kh=2 key-split, wave = 32q x 128c,
// block = 4 waves, grid = 512 (2 blocks/CU). K staged in LDS (swz4), V dbuf,
// wave-private P. Bare-exp2 softmax, unnormalized partials + L.
// FROZEN: kh=3 (r12,r16) and unroll-2 (r14) all regressed. Do not perturb.
// ---------------------------------------------------------------------------
__global__ __launch_bounds__(256, 2) void flash_kernel(
    const __hip_bfloat16* __restrict__ qg, const __hip_bfloat16* __restrict__ kg,
    const __hip_bfloat16* __restrict__ vg,
    __hip_bfloat16* __restrict__ ph0, __hip_bfloat16* __restrict__ ph1,
    float* __restrict__ Lh)
{
    __shared__ __hip_bfloat16 v_lds[2][128 * 64];  // 32 KB [c][64k]
    __shared__ __hip_bfloat16 k_lds[2][64 * 32];   // 8 KB [key][32d]
    __shared__ __hip_bfloat16 p_lds[4][32 * 64];   // 16 KB wave-private [q][64k]

    int blk = blockIdx.x;
    int work = (blk & 7) * 64 + (blk >> 3);
    int g = work >> 6;
    int kh = g >> 2, cs = (g >> 1) & 1, bl = g & 1;
    int rem = work & 63;
    int b = ((rem >> 5) << 1) | bl;
    int qgp = rem & 31;
    int t = threadIdx.x, w = t >> 6, lane = t & 63;
    int l15 = lane & 15, l4 = lane >> 4;
    int qw = qgp * 128 + w * 32;

    short8 qf[2];
#pragma unroll
    for (int qs = 0; qs < 2; ++qs)
        qf[qs] = *(const short8*)&qg[((size_t)(b * N_TOK + qw + qs * 16 + l15)) * 32 + l4 * 8];

    f32x4 zf = {0.f, 0.f, 0.f, 0.f};
    f32x4 acc[2][8];
#pragma unroll
    for (int qs = 0; qs < 2; ++qs)
#pragma unroll
        for (int ct = 0; ct < 8; ++ct) acc[qs][ct] = zf;
    float Lr[2] = {0.f, 0.f};

    int vc  = t >> 1;
    int kb4 = (t & 1) * 4;
    int kr  = t >> 2;
    int kch = t & 3;

    const __hip_bfloat16* vrow  = &vg[((size_t)(b * 256 + cs * 128 + vc)) * N_TOK + kh * 2048];
    const __hip_bfloat16* kbase = &kg[((size_t)(b * N_TOK + kh * 2048)) * 32];

    uint4 vp[4], kp;

#pragma unroll
    for (int j = 0; j < 4; ++j)
        vp[j] = *(const uint4*)&vrow[(kb4 + j) * 8];
    kp = *(const uint4*)&kbase[kr * 32 + kch * 8];
#pragma unroll
    for (int j = 0; j < 4; ++j)
        *(uint4*)&v_lds[0][vc * 64 + (((2 * (kb4 + j)) ^ (vc & 14)) << 2)] = vp[j];
    *(uint4*)&k_lds[0][kr * 32 + swz4(kch, kr) * 8] = kp;
    __syncthreads();

    int buf = 0;
    for (int it = 0; it < 32; ++it) {
        int nm0 = it * 64 + 64;
        bool more = (it < 31);
        if (more) {
#pragma unroll
            for (int j = 0; j < 4; ++j)
                vp[j] = *(const uint4*)&vrow[nm0 + (kb4 + j) * 8];
            kp = *(const uint4*)&kbase[(size_t)(nm0 + kr) * 32 + kch * 8];
        }

        short8 kf[4];
#pragma unroll
        for (int kt = 0; kt < 4; ++kt) {
            int row = kt * 16 + l15;
            kf[kt] = *(const short8*)&k_lds[buf][row * 32 + swz4(l4, row) * 8];
        }
        f32x4 sf[2][4];
#pragma unroll
        for (int qs = 0; qs < 2; ++qs)
#pragma unroll
            for (int kt = 0; kt < 4; ++kt)
                sf[qs][kt] = MFMA16(kf[kt], qf[qs], zf);

        // ---- bare exp2 (scale folded into q; no shift needed)
#pragma unroll
        for (int qs = 0; qs < 2; ++qs) {
            int prow = qs * 16 + l15;
#pragma unroll
            for (int kt = 0; kt < 4; ++kt) {
                float p0 = exp2f(sf[qs][kt][0]);
                float p1 = exp2f(sf[qs][kt][1]);
                float p2 = exp2f(sf[qs][kt][2]);
                float p3 = exp2f(sf[qs][kt][3]);
                Lr[qs] += (p0 + p1) + (p2 + p3);
                uint2 u;
                u.x = pack_bf16x2(p0, p1);
                u.y = pack_bf16x2(p2, p3);
                *(uint2*)&p_lds[w][prow * 64 + (((kt * 4 + l4) ^ (l15 & 14)) << 2)] = u;
            }
        }

#pragma unroll
        for (int ks = 0; ks < 2; ++ks) {
            short8 pb[2];
#pragma unroll
            for (int qs = 0; qs < 2; ++qs)
                pb[qs] = *(const short8*)&p_lds[w][(qs * 16 + l15) * 64 +
                         (((ks * 8 + l4 * 2) ^ (l15 & 14)) << 2)];
#pragma unroll
            for (int ct = 0; ct < 8; ++ct) {
                int cr = ct * 16 + l15;
                short8 vf = *(const short8*)&v_lds[buf][cr * 64 +
                           (((ks * 8 + l4 * 2) ^ (cr & 14)) << 2)];
                acc[0][ct] = MFMA16(vf, pb[0], acc[0][ct]);
                acc[1][ct] = MFMA16(vf, pb[1], acc[1][ct]);
            }
        }

        if (more) {
#pragma unroll
            for (int j = 0; j < 4; ++j)
                *(uint4*)&v_lds[buf ^ 1][vc * 64 + (((2 * (kb4 + j)) ^ (vc & 14)) << 2)] = vp[j];
            *(uint4*)&k_lds[buf ^ 1][kr * 32 + swz4(kch, kr) * 8] = kp;
            buf ^= 1;
        }
        __syncthreads();
    }

#pragma unroll
    for (int qs = 0; qs < 2; ++qs) {
        float L = Lr[qs];
        L += __shfl_xor(L, 16);
        L += __shfl_xor(L, 32);
        int nq = qw + qs * 16 + l15;
        if (cs == 0 && l4 == 0)
            Lh[kh * 16384 + b * 4096 + nq] = L;
        __hip_bfloat16* pdst = kh ? ph1 : ph0;
        size_t pix = (size_t)(b * N_TOK + nq);
#pragma unroll
        for (int ct = 0; ct < 8; ++ct) {
            int cl = cs * 128 + ct * 16 + l4 * 4;
            uint2 u;
            u.x = pack_bf16x2(acc[qs][ct][0], acc[qs][ct][1]);
            u.y = pack_bf16x2(acc[qs][ct][2], acc[qs][ct][3]);
            *(uint2*)&pdst[pix * 256 + cl] = u;
        }
    }
}

// ---------------------------------------------------------------------------
// Combine (r8-proven): att = (ph0 + ph1) / (L0 + L1). att aliases ph1.
// ---------------------------------------------------------------------------
__global__ __launch_bounds__(256) void combine_kernel(
    const __hip_bfloat16* __restrict__ ph0, const __hip_bfloat16* __restrict__ ph1,
    const float* __restrict__ Lh, __hip_bfloat16* __restrict__ att)
{
    int idx = blockIdx.x * 256 + threadIdx.x;   // 524288 threads, 8 ch each
    size_t e = (size_t)idx * 8;
    int bn = (int)(e >> 8);
    float inv = 1.f / (Lh[bn] + Lh[16384 + bn]);
    uint4 a = *(const uint4*)&ph0[e];
    uint4 b4 = *(const uint4*)&ph1[e];
    const unsigned* ap = (const unsigned*)&a;
    const unsigned* bp = (const unsigned*)&b4;
    uint4 o;
    unsigned* op = (unsigned*)&o;
#pragma unroll
    for (int j = 0; j < 4; ++j) {
        float lo = (bf2f((unsigned short)(ap[j] & 0xffff)) +
                    bf2f((unsigned short)(bp[j] & 0xffff))) * inv;
        float hi = (bf2f((unsigned short)(ap[j] >> 16)) +
                    bf2f((unsigned short)(bp[j] >> 16))) * inv;
        op[j] = pack_bf16x2(lo, hi);
    }
    *(uint4*)&att[e] = o;
}

// ---------------------------------------------------------------------------
// Implicit-GEMM 3x3 conv via MFMA + bias + BN + ReLU + residual.
// v4: o32 (grid 1024, 4 blocks/CU), spatial 16x8. Staging reads the single
// pre-combined att buffer (one uint4 load per chunk — no Lh, no combine VALU).
// ---------------------------------------------------------------------------
__global__ __launch_bounds__(256) void conv_mfma_kernel(
    const __hip_bfloat16* __restrict__ att, const __hip_bfloat16* __restrict__ Wt,
    const float* __restrict__ bo,  const float* __restrict__ gamma,
    const float* __restrict__ beta, const float* __restrict__ mean,
    const float* __restrict__ var, const float* __restrict__ x,
    float* __restrict__ out)
{
    __shared__ __hip_bfloat16 in_lds[180 * 32];     // [10x18 halo][32c] swz
    __shared__ __hip_bfloat16 wt_lds[9 * 32 * 32];  // [tap][o32][32c] swz

    int blk = blockIdx.x;
    int sp = blk & 31, ob = (blk >> 5) & 7, b = blk >> 8;
    int y0 = (sp >> 2) * 8, x0 = (sp & 3) * 16;
    int o0 = ob * 32;
    int t = threadIdx.x;
    int w = t >> 6, lane = t & 63;
    int l15 = lane & 15, l4 = lane >> 4;

    f32x4 zf = {0.f, 0.f, 0.f, 0.f};
    f32x4 acc[2][2];   // [m][ntw]
#pragma unroll
    for (int m = 0; m < 2; ++m)
#pragma unroll
        for (int n = 0; n < 2; ++n) acc[m][n] = zf;

    for (int cc = 0; cc < 256; cc += 32) {
        __syncthreads();
        for (int jj = t; jj < 720; jj += 256) {
            int pix = jj >> 2, h = jj & 3;
            int iy = pix / 18, ix = pix - iy * 18;
            int gy = y0 - 1 + iy, gx = x0 - 1 + ix;
            uint4 val = {0u, 0u, 0u, 0u};
            if (gy >= 0 && gy < 64 && gx >= 0 && gx < 64)
                val = *(const uint4*)&att[((size_t)(b * 4096 + gy * 64 + gx)) * 256 + cc + h * 8];
            *(uint4*)&in_lds[pix * 32 + swz4(h, pix) * 8] = val;
        }
        for (int jj = t; jj < 1152; jj += 256) {
            int tap = jj >> 7, rem = jj & 127;
            int o = rem >> 2, h = rem & 3;
            uint4 wv = *(const uint4*)&Wt[((size_t)(tap * 256 + o0 + o)) * 256 + cc + h * 8];
            *(uint4*)&wt_lds[tap * 1024 + o * 32 + swz4(h, o) * 8] = wv;
        }
        __syncthreads();

#pragma unroll
        for (int ky = 0; ky < 3; ++ky) {
#pragma unroll
            for (int kx = 0; kx < 3; ++kx) {
                int tap = ky * 3 + kx;
                short8 af[2];
#pragma unroll
                for (int m = 0; m < 2; ++m) {
                    int orow = m * 16 + l15;
                    af[m] = *(const short8*)&wt_lds[tap * 1024 + orow * 32 + swz4(l4, orow) * 8];
                }
#pragma unroll
                for (int ntw = 0; ntw < 2; ++ntw) {
                    int yy = w * 2 + ntw;
                    int p = (yy + ky) * 18 + kx + l15;
                    short8 bfr = *(const short8*)&in_lds[p * 32 + swz4(l4, p) * 8];
#pragma unroll
                    for (int m = 0; m < 2; ++m)
                        acc[m][ntw] = MFMA16(af[m], bfr, acc[m][ntw]);
                }
            }
        }
    }

#pragma unroll
    for (int m = 0; m < 2; ++m) {
#pragma unroll
        for (int r = 0; r < 4; ++r) {
            int oc = o0 + m * 16 + l4 * 4 + r;
            float inv = gamma[oc] * rsqrtf(var[oc] + 1e-5f);
            float sh  = (bo[oc] - mean[oc]) * inv + beta[oc];
#pragma unroll
            for (int ntw = 0; ntw < 2; ++ntw) {
                int gy = y0 + w * 2 + ntw, gx = x0 + l15;
                size_t idx = (size_t)(b * 256 + oc) * 4096 + (size_t)gy * 64 + gx;
                float yv = acc[m][ntw][r] * inv + sh;
                yv = fmaxf(yv, 0.f);
                out[idx] = yv + x[idx];
            }
        }
    }
}

// ---------------------------------------------------------------------------
extern "C" void kernel_launch(void* const* d_in, const int* in_sizes, int n_in,
                              void* d_out, int out_size, void* d_ws, size_t ws_size,
                              hipStream_t stream)
{
    const float* x  = (const float*)d_in[0];
    const float* Wq = (const float*)d_in[1];
    const float* bq = (const float*)d_in[2];
    const float* Wk = (const float*)d_in[3];
    const float* bk = (const float*)d_in[4];
    const float* Wv = (const float*)d_in[5];
    const float* bv = (const float*)d_in[6];
    const float* Wo = (const float*)d_in[7];
    const float* bo = (const float*)d_in[8];
    const float* gm = (const float*)d_in[9];
    const float* bt = (const float*)d_in[10];
    const float* mn = (const float*)d_in[11];
    const float* vr = (const float*)d_in[12];
    float* out = (float*)d_out;

    char* wsb = (char*)d_ws;
    __hip_bfloat16* qg  = (__hip_bfloat16*)(wsb);                      // 1 MB
    __hip_bfloat16* kg  = (__hip_bfloat16*)(wsb + (1u  << 20));        // 1 MB
    __hip_bfloat16* vg  = (__hip_bfloat16*)(wsb + (2u  << 20));        // 8 MB
    __hip_bfloat16* ph1 = (__hip_bfloat16*)(wsb + (10u << 20));        // 8 MB (= att)
    __hip_bfloat16* Wt  = (__hip_bfloat16*)(wsb + (18u << 20));        // 1.2 MB
    __hip_bfloat16* ph0 = (__hip_bfloat16*)(wsb + (20u << 20));        // 8 MB
    __hip_bfloat16* Wqk = (__hip_bfloat16*)(wsb + (28u << 20));        // 32 KB
    __hip_bfloat16* Wvb = (__hip_bfloat16*)(wsb + (28u << 20) + 65536);// 128 KB
    float*          Lh  = (float*)(wsb + (28u << 20) + 262144);        // 128 KB

    __hip_bfloat16* att = ph1;  // combine writes in place (elementwise)

    w_prep_kernel  <<<261,  256, 0, stream>>>(Wo, Wq, Wk, Wv, Wt, Wqk, Wvb);
    qkv_kernel     <<<512,  256, 0, stream>>>(x, Wqk, Wvb, bq, bk, bv, qg, kg, vg);
    flash_kernel   <<<512,  256, 0, stream>>>(qg, kg, vg, ph0, ph1, Lh);
    combine_kernel <<<2048, 256, 0, stream>>>(ph0, ph1, Lh, att);
    conv_mfma_kernel<<<1024, 256, 0, stream>>>(att, Wt, bo, gm, bt, mn, vr, x, out);
}

// Round 19
// 141.473 us; speedup vs baseline: 1.2363x; 1.0007x over previous
//
#include <hip/hip_runtime.h>
#include <hip/hip_bf16.h>
#include <math.h>

#define N_TOK 4096

typedef __attribute__((ext_vector_type(8))) short short8;
typedef __attribute__((ext_vector_type(4))) float f32x4;

#define MFMA16(a, b, c) __builtin_amdgcn_mfma_f32_16x16x32_bf16(a, b, c, 0, 0, 0)

__device__ inline unsigned pack_bf16x2(float a, float b) {
    __hip_bfloat16 ha = __float2bfloat16(a), hb = __float2bfloat16(b);
    unsigned short ua = *(unsigned short*)&ha, ub = *(unsigned short*)&hb;
    return (unsigned)ua | ((unsigned)ub << 16);
}

__device__ inline float bf2f(unsigned short u) {
    unsigned v = ((unsigned)u) << 16;
    union { unsigned u; float f; } cv; cv.u = v; return cv.f;
}

// swizzled 16B-chunk slot for row-stride-64B LDS tiles (<=2-way conflicts)
__device__ inline int swz4(int h, int row) { return (h ^ row ^ (row >> 2)) & 3; }

// scale * log2(e), folded into q at projection time
#define SCK 0.25506974748975505f

// ---------------------------------------------------------------------------
// Weight prep: Wo->Wt[tap][o][c] bf16 ; Wq,Wk->Wqk[64][256] ; Wv->Wvb bf16
// ---------------------------------------------------------------------------
__global__ __launch_bounds__(256) void w_prep_kernel(
    const float* __restrict__ Wo, const float* __restrict__ Wq,
    const float* __restrict__ Wk, const float* __restrict__ Wv,
    __hip_bfloat16* __restrict__ Wt, __hip_bfloat16* __restrict__ Wqk,
    __hip_bfloat16* __restrict__ Wvb)
{
    int blk = blockIdx.x, t = threadIdx.x;
    if (blk < 256) {
        const float* src = &Wo[(size_t)(blk * 256 + t) * 9];
#pragma unroll
        for (int tap = 0; tap < 9; ++tap)
            Wt[(size_t)(tap * 256 + blk) * 256 + t] = __float2bfloat16(src[tap]);
    } else if (blk < 260) {
        int r0 = (blk - 256) * 64;
        for (int r = r0; r < r0 + 64; ++r)
            Wvb[r * 256 + t] = __float2bfloat16(Wv[r * 256 + t]);
    } else {
        for (int r = 0; r < 32; ++r) {
            // q rows pre-scaled by SCK (softmax scale * log2e folded in)
            Wqk[r * 256 + t]        = __float2bfloat16(Wq[r * 256 + t] * SCK);
            Wqk[(r + 32) * 256 + t] = __float2bfloat16(Wk[r * 256 + t]);
        }
    }
}

// ---------------------------------------------------------------------------
// Fused QKV projection v3: block = 16 n (grid B*256 = 1024, 4 blocks/CU).
// All 4 waves share the block's 16-n B-frag; wave w owns 5 of 20 m-tiles
// (tiles 0-3 = q0,q1,k0,k1 ; tiles 4-19 = v[0..15]). Staging: 64c x 16n
// transposed tile, 1 float4/thread/chunk.
// ---------------------------------------------------------------------------
__global__ __launch_bounds__(256) void qkv_kernel(
    const float* __restrict__ x,
    const __hip_bfloat16* __restrict__ Wqk, const __hip_bfloat16* __restrict__ Wvb,
    const float* __restrict__ bq, const float* __restrict__ bk,
    const float* __restrict__ bv,
    __hip_bfloat16* __restrict__ qg, __hip_bfloat16* __restrict__ kg,
    __hip_bfloat16* __restrict__ vg)
{
    __shared__ __hip_bfloat16 tl[16][72];   // [n][c-chunk] pad 8
    int blk = blockIdx.x;
    int b = blk >> 8, n0 = (blk & 255) * 16;
    int t = threadIdx.x, w = t >> 6, lane = t & 63;
    int l15 = lane & 15, l4 = lane >> 4;
    int n = n0 + l15;

    // wave's 5 A-row base pointers (tiles w*5 .. w*5+4)
    const __hip_bfloat16* wrow[5];
#pragma unroll
    for (int mi = 0; mi < 5; ++mi) {
        int ti = w * 5 + mi;
        wrow[mi] = (ti < 4) ? &Wqk[(size_t)(ti * 16 + l15) * 256]
                            : &Wvb[(size_t)((ti - 4) * 16 + l15) * 256];
    }

    f32x4 zf = {0.f, 0.f, 0.f, 0.f};
    f32x4 acc[5];
#pragma unroll
    for (int m = 0; m < 5; ++m) acc[m] = zf;

    for (int cc = 0; cc < 256; cc += 64) {
        __syncthreads();
        {   // stage 64c x 16n transposed -> tl (1 float4/thread)
            int c = t >> 2, n4 = (t & 3) * 4;
            float4 v4 = *(const float4*)&x[((size_t)(b * 256 + cc + c)) * N_TOK + n0 + n4];
            tl[n4 + 0][c] = __float2bfloat16(v4.x);
            tl[n4 + 1][c] = __float2bfloat16(v4.y);
            tl[n4 + 2][c] = __float2bfloat16(v4.z);
            tl[n4 + 3][c] = __float2bfloat16(v4.w);
        }
        __syncthreads();
#pragma unroll
        for (int kk = 0; kk < 2; ++kk) {
            short8 bfr = *(const short8*)&tl[l15][kk * 32 + l4 * 8];
#pragma unroll
            for (int mi = 0; mi < 5; ++mi) {
                short8 af = *(const short8*)&wrow[mi][cc + kk * 32 + l4 * 8];
                acc[mi] = MFMA16(af, bfr, acc[mi]);
            }
        }
    }

    // epilogue (wave-uniform branches per tile)
#pragma unroll
    for (int mi = 0; mi < 5; ++mi) {
        int ti = w * 5 + mi;
        if (ti < 2) {            // q tiles: bias*SCK, (B,N,32)
            int oofs = ti * 16 + l4 * 4;
            f32x4 bb = *(const f32x4*)&bq[oofs];
            uint2 u;
            u.x = pack_bf16x2(acc[mi][0] + bb[0] * SCK, acc[mi][1] + bb[1] * SCK);
            u.y = pack_bf16x2(acc[mi][2] + bb[2] * SCK, acc[mi][3] + bb[3] * SCK);
            *(uint2*)&qg[((size_t)(b * N_TOK + n)) * 32 + oofs] = u;
        } else if (ti < 4) {     // k tiles
            int oofs = (ti - 2) * 16 + l4 * 4;
            f32x4 bb = *(const f32x4*)&bk[oofs];
            uint2 u;
            u.x = pack_bf16x2(acc[mi][0] + bb[0], acc[mi][1] + bb[1]);
            u.y = pack_bf16x2(acc[mi][2] + bb[2], acc[mi][3] + bb[3]);
            *(uint2*)&kg[((size_t)(b * N_TOK + n)) * 32 + oofs] = u;
        } else {                 // v tiles: (B,C,N)
            int cb = (ti - 4) * 16 + l4 * 4;
            f32x4 bvv = *(const f32x4*)&bv[cb];
#pragma unroll
            for (int r = 0; r < 4; ++r)
                vg[((size_t)(b * 256 + cb + r)) * N_TOK + n] = __float2bfloat16(acc[mi][r] + bvv[r]);
        }
    }
}

// ---------------------------------------------------------------------------
// Flash v8 (r13-proven, byte-identical): kh=2 key-split, wave = 32q x 128c,
// block = 4 waves, grid = 512 (2 blocks/CU). K staged in LDS (swz4), V dbuf,
// wave-private P. Bare-exp2 softmax, unnormalized partials + L.
// FROZEN: kh=3 (r12,r16) and unroll-2 (r14) all regressed. Do not perturb.
// ---------------------------------------------------------------------------
__global__ __launch_bounds__(256, 2) void flash_kernel(
    const __hip_bfloat16* __restrict__ qg, const __hip_bfloat16* __restrict__ kg,
    const __hip_bfloat16* __restrict__ vg,
    __hip_bfloat16* __restrict__ ph0, __hip_bfloat16* __restrict__ ph1,
    float* __restrict__ Lh)
{
    __shared__ __hip_bfloat16 v_lds[2][128 * 64];  // 32 KB [c][64k]
    __shared__ __hip_bfloat16 k_lds[2][64 * 32];   // 8 KB [key][32d]
    __shared__ __hip_bfloat16 p_lds[4][32 * 64];   // 16 KB wave-private [q][64k]

    int blk = blockIdx.x;
    int work = (blk & 7) * 64 + (blk >> 3);
    int g = work >> 6;
    int kh = g >> 2, cs = (g >> 1) & 1, bl = g & 1;
    int rem = work & 63;
    int b = ((rem >> 5) << 1) | bl;
    int qgp = rem & 31;
    int t = threadIdx.x, w = t >> 6, lane = t & 63;
    int l15 = lane & 15, l4 = lane >> 4;
    int qw = qgp * 128 + w * 32;

    short8 qf[2];
#pragma unroll
    for (int qs = 0; qs < 2; ++qs)
        qf[qs] = *(const short8*)&qg[((size_t)(b * N_TOK + qw + qs * 16 + l15)) * 32 + l4 * 8];

    f32x4 zf = {0.f, 0.f, 0.f, 0.f};
    f32x4 acc[2][8];
#pragma unroll
    for (int qs = 0; qs < 2; ++qs)
#pragma unroll
        for (int ct = 0; ct < 8; ++ct) acc[qs][ct] = zf;
    float Lr[2] = {0.f, 0.f};

    int vc  = t >> 1;
    int kb4 = (t & 1) * 4;
    int kr  = t >> 2;
    int kch = t & 3;

    const __hip_bfloat16* vrow  = &vg[((size_t)(b * 256 + cs * 128 + vc)) * N_TOK + kh * 2048];
    const __hip_bfloat16* kbase = &kg[((size_t)(b * N_TOK + kh * 2048)) * 32];

    uint4 vp[4], kp;

#pragma unroll
    for (int j = 0; j < 4; ++j)
        vp[j] = *(const uint4*)&vrow[(kb4 + j) * 8];
    kp = *(const uint4*)&kbase[kr * 32 + kch * 8];
#pragma unroll
    for (int j = 0; j < 4; ++j)
        *(uint4*)&v_lds[0][vc * 64 + (((2 * (kb4 + j)) ^ (vc & 14)) << 2)] = vp[j];
    *(uint4*)&k_lds[0][kr * 32 + swz4(kch, kr) * 8] = kp;
    __syncthreads();

    int buf = 0;
    for (int it = 0; it < 32; ++it) {
        int nm0 = it * 64 + 64;
        bool more = (it < 31);
        if (more) {
#pragma unroll
            for (int j = 0; j < 4; ++j)
                vp[j] = *(const uint4*)&vrow[nm0 + (kb4 + j) * 8];
            kp = *(const uint4*)&kbase[(size_t)(nm0 + kr) * 32 + kch * 8];
        }

        short8 kf[4];
#pragma unroll
        for (int kt = 0; kt < 4; ++kt) {
            int row = kt * 16 + l15;
            kf[kt] = *(const short8*)&k_lds[buf][row * 32 + swz4(l4, row) * 8];
        }
        f32x4 sf[2][4];
#pragma unroll
        for (int qs = 0; qs < 2; ++qs)
#pragma unroll
            for (int kt = 0; kt < 4; ++kt)
                sf[qs][kt] = MFMA16(kf[kt], qf[qs], zf);

        // ---- bare exp2 (scale folded into q; no shift needed)
#pragma unroll
        for (int qs = 0; qs < 2; ++qs) {
            int prow = qs * 16 + l15;
#pragma unroll
            for (int kt = 0; kt < 4; ++kt) {
                float p0 = exp2f(sf[qs][kt][0]);
                float p1 = exp2f(sf[qs][kt][1]);
                float p2 = exp2f(sf[qs][kt][2]);
                float p3 = exp2f(sf[qs][kt][3]);
                Lr[qs] += (p0 + p1) + (p2 + p3);
                uint2 u;
                u.x = pack_bf16x2(p0, p1);
                u.y = pack_bf16x2(p2, p3);
                *(uint2*)&p_lds[w][prow * 64 + (((kt * 4 + l4) ^ (l15 & 14)) << 2)] = u;
            }
        }

#pragma unroll
        for (int ks = 0; ks < 2; ++ks) {
            short8 pb[2];
#pragma unroll
            for (int qs = 0; qs < 2; ++qs)
                pb[qs] = *(const short8*)&p_lds[w][(qs * 16 + l15) * 64 +
                         (((ks * 8 + l4 * 2) ^ (l15 & 14)) << 2)];
#pragma unroll
            for (int ct = 0; ct < 8; ++ct) {
                int cr = ct * 16 + l15;
                short8 vf = *(const short8*)&v_lds[buf][cr * 64 +
                           (((ks * 8 + l4 * 2) ^ (cr & 14)) << 2)];
                acc[0][ct] = MFMA16(vf, pb[0], acc[0][ct]);
                acc[1][ct] = MFMA16(vf, pb[1], acc[1][ct]);
            }
        }

        if (more) {
#pragma unroll
            for (int j = 0; j < 4; ++j)
                *(uint4*)&v_lds[buf ^ 1][vc * 64 + (((2 * (kb4 + j)) ^ (vc & 14)) << 2)] = vp[j];
            *(uint4*)&k_lds[buf ^ 1][kr * 32 + swz4(kch, kr) * 8] = kp;
            buf ^= 1;
        }
        __syncthreads();
    }

#pragma unroll
    for (int qs = 0; qs < 2; ++qs) {
        float L = Lr[qs];
        L += __shfl_xor(L, 16);
        L += __shfl_xor(L, 32);
        int nq = qw + qs * 16 + l15;
        if (cs == 0 && l4 == 0)
            Lh[kh * 16384 + b * 4096 + nq] = L;
        __hip_bfloat16* pdst = kh ? ph1 : ph0;
        size_t pix = (size_t)(b * N_TOK + nq);
#pragma unroll
        for (int ct = 0; ct < 8; ++ct) {
            int cl = cs * 128 + ct * 16 + l4 * 4;
            uint2 u;
            u.x = pack_bf16x2(acc[qs][ct][0], acc[qs][ct][1]);
            u.y = pack_bf16x2(acc[qs][ct][2], acc[qs][ct][3]);
            *(uint2*)&pdst[pix * 256 + cl] = u;
        }
    }
}

// ---------------------------------------------------------------------------
// Combine (r8-proven): att = (ph0 + ph1) / (L0 + L1). att aliases ph1.
// ---------------------------------------------------------------------------
__global__ __launch_bounds__(256) void combine_kernel(
    const __hip_bfloat16* __restrict__ ph0, const __hip_bfloat16* __restrict__ ph1,
    const float* __restrict__ Lh, __hip_bfloat16* __restrict__ att)
{
    int idx = blockIdx.x * 256 + threadIdx.x;   // 524288 threads, 8 ch each
    size_t e = (size_t)idx * 8;
    int bn = (int)(e >> 8);
    float inv = 1.f / (Lh[bn] + Lh[16384 + bn]);
    uint4 a = *(const uint4*)&ph0[e];
    uint4 b4 = *(const uint4*)&ph1[e];
    const unsigned* ap = (const unsigned*)&a;
    const unsigned* bp = (const unsigned*)&b4;
    uint4 o;
    unsigned* op = (unsigned*)&o;
#pragma unroll
    for (int j = 0; j < 4; ++j) {
        float lo = (bf2f((unsigned short)(ap[j] & 0xffff)) +
                    bf2f((unsigned short)(bp[j] & 0xffff))) * inv;
        float hi = (bf2f((unsigned short)(ap[j] >> 16)) +
                    bf2f((unsigned short)(bp[j] >> 16))) * inv;
        op[j] = pack_bf16x2(lo, hi);
    }
    *(uint4*)&att[e] = o;
}

// ---------------------------------------------------------------------------
// Implicit-GEMM 3x3 conv via MFMA + bias + BN + ReLU + residual.
// v4 (r18-proven): o32 (grid 1024, 4 blocks/CU), spatial 16x8; staging reads
// the single pre-combined att buffer.
// ---------------------------------------------------------------------------
__global__ __launch_bounds__(256) void conv_mfma_kernel(
    const __hip_bfloat16* __restrict__ att, const __hip_bfloat16* __restrict__ Wt,
    const float* __restrict__ bo,  const float* __restrict__ gamma,
    const float* __restrict__ beta, const float* __restrict__ mean,
    const float* __restrict__ var, const float* __restrict__ x,
    float* __restrict__ out)
{
    __shared__ __hip_bfloat16 in_lds[180 * 32];     // [10x18 halo][32c] swz
    __shared__ __hip_bfloat16 wt_lds[9 * 32 * 32];  // [tap][o32][32c] swz

    int blk = blockIdx.x;
    int sp = blk & 31, ob = (blk >> 5) & 7, b = blk >> 8;
    int y0 = (sp >> 2) * 8, x0 = (sp & 3) * 16;
    int o0 = ob * 32;
    int t = threadIdx.x;
    int w = t >> 6, lane = t & 63;
    int l15 = lane & 15, l4 = lane >> 4;

    f32x4 zf = {0.f, 0.f, 0.f, 0.f};
    f32x4 acc[2][2];   // [m][ntw]
#pragma unroll
    for (int m = 0; m < 2; ++m)
#pragma unroll
        for (int n = 0; n < 2; ++n) acc[m][n] = zf;

    for (int cc = 0; cc < 256; cc += 32) {
        __syncthreads();
        for (int jj = t; jj < 720; jj += 256) {
            int pix = jj >> 2, h = jj & 3;
            int iy = pix / 18, ix = pix - iy * 18;
            int gy = y0 - 1 + iy, gx = x0 - 1 + ix;
            uint4 val = {0u, 0u, 0u, 0u};
            if (gy >= 0 && gy < 64 && gx >= 0 && gx < 64)
                val = *(const uint4*)&att[((size_t)(b * 4096 + gy * 64 + gx)) * 256 + cc + h * 8];
            *(uint4*)&in_lds[pix * 32 + swz4(h, pix) * 8] = val;
        }
        for (int jj = t; jj < 1152; jj += 256) {
            int tap = jj >> 7, rem = jj & 127;
            int o = rem >> 2, h = rem & 3;
            uint4 wv = *(const uint4*)&Wt[((size_t)(tap * 256 + o0 + o)) * 256 + cc + h * 8];
            *(uint4*)&wt_lds[tap * 1024 + o * 32 + swz4(h, o) * 8] = wv;
        }
        __syncthreads();

#pragma unroll
        for (int ky = 0; ky < 3; ++ky) {
#pragma unroll
            for (int kx = 0; kx < 3; ++kx) {
                int tap = ky * 3 + kx;
                short8 af[2];
#pragma unroll
                for (int m = 0; m < 2; ++m) {
                    int orow = m * 16 + l15;
                    af[m] = *(const short8*)&wt_lds[tap * 1024 + orow * 32 + swz4(l4, orow) * 8];
                }
#pragma unroll
                for (int ntw = 0; ntw < 2; ++ntw) {
                    int yy = w * 2 + ntw;
                    int p = (yy + ky) * 18 + kx + l15;
                    short8 bfr = *(const short8*)&in_lds[p * 32 + swz4(l4, p) * 8];
#pragma unroll
                    for (int m = 0; m < 2; ++m)
                        acc[m][ntw] = MFMA16(af[m], bfr, acc[m][ntw]);
                }
            }
        }
    }

#pragma unroll
    for (int m = 0; m < 2; ++m) {
#pragma unroll
        for (int r = 0; r < 4; ++r) {
            int oc = o0 + m * 16 + l4 * 4 + r;
            float inv = gamma[oc] * rsqrtf(var[oc] + 1e-5f);
            float sh  = (bo[oc] - mean[oc]) * inv + beta[oc];
#pragma unroll
            for (int ntw = 0; ntw < 2; ++ntw) {
                int gy = y0 + w * 2 + ntw, gx = x0 + l15;
                size_t idx = (size_t)(b * 256 + oc) * 4096 + (size_t)gy * 64 + gx;
                float yv = acc[m][ntw][r] * inv + sh;
                yv = fmaxf(yv, 0.f);
                out[idx] = yv + x[idx];
            }
        }
    }
}

// ---------------------------------------------------------------------------
extern "C" void kernel_launch(void* const* d_in, const int* in_sizes, int n_in,
                              void* d_out, int out_size, void* d_ws, size_t ws_size,
                              hipStream_t stream)
{
    const float* x  = (const float*)d_in[0];
    const float* Wq = (const float*)d_in[1];
    const float* bq = (const float*)d_in[2];
    const float* Wk = (const float*)d_in[3];
    const float* bk = (const float*)d_in[4];
    const float* Wv = (const float*)d_in[5];
    const float* bv = (const float*)d_in[6];
    const float* Wo = (const float*)d_in[7];
    const float* bo = (const float*)d_in[8];
    const float* gm = (const float*)d_in[9];
    const float* bt = (const float*)d_in[10];
    const float* mn = (const float*)d_in[11];
    const float* vr = (const float*)d_in[12];
    float* out = (float*)d_out;

    char* wsb = (char*)d_ws;
    __hip_bfloat16* qg  = (__hip_bfloat16*)(wsb);                      // 1 MB
    __hip_bfloat16* kg  = (__hip_bfloat16*)(wsb + (1u  << 20));        // 1 MB
    __hip_bfloat16* vg  = (__hip_bfloat16*)(wsb + (2u  << 20));        // 8 MB
    __hip_bfloat16* ph1 = (__hip_bfloat16*)(wsb + (10u << 20));        // 8 MB (= att)
    __hip_bfloat16* Wt  = (__hip_bfloat16*)(wsb + (18u << 20));        // 1.2 MB
    __hip_bfloat16* ph0 = (__hip_bfloat16*)(wsb + (20u << 20));        // 8 MB
    __hip_bfloat16* Wqk = (__hip_bfloat16*)(wsb + (28u << 20));        // 32 KB
    __hip_bfloat16* Wvb = (__hip_bfloat16*)(wsb + (28u << 20) + 65536);// 128 KB
    float*          Lh  = (float*)(wsb + (28u << 20) + 262144);        // 128 KB

    __hip_bfloat16* att = ph1;  // combine writes in place (elementwise)

    w_prep_kernel  <<<261,  256, 0, stream>>>(Wo, Wq, Wk, Wv, Wt, Wqk, Wvb);
    qkv_kernel     <<<1024, 256, 0, stream>>>(x, Wqk, Wvb, bq, bk, bv, qg, kg, vg);
    flash_kernel   <<<512,  256, 0, stream>>>(qg, kg, vg, ph0, ph1, Lh);
    combine_kernel <<<2048, 256, 0, stream>>>(ph0, ph1, Lh, att);
    conv_mfma_kernel<<<1024, 256, 0, stream>>>(att, Wt, bo, gm, bt, mn, vr, x, out);
}

// Round 20
// 139.063 us; speedup vs baseline: 1.2577x; 1.0173x over previous
//
#include <hip/hip_runtime.h>
#include <hip/hip_bf16.h>
#include <math.h>

#define N_TOK 4096

typedef __attribute__((ext_vector_type(8))) short short8;
typedef __attribute__((ext_vector_type(4))) float f32x4;

#define MFMA16(a, b, c) __builtin_amdgcn_mfma_f32_16x16x32_bf16(a, b, c, 0, 0, 0)

__device__ inline unsigned pack_bf16x2(float a, float b) {
    __hip_bfloat16 ha = __float2bfloat16(a), hb = __float2bfloat16(b);
    unsigned short ua = *(unsigned short*)&ha, ub = *(unsigned short*)&hb;
    return (unsigned)ua | ((unsigned)ub << 16);
}

__device__ inline float bf2f(unsigned short u) {
    unsigned v = ((unsigned)u) << 16;
    union { unsigned u; float f; } cv; cv.u = v; return cv.f;
}

// swizzled 16B-chunk slot for row-stride-64B LDS tiles (<=2-way conflicts)
__device__ inline int swz4(int h, int row) { return (h ^ row ^ (row >> 2)) & 3; }

// scale * log2(e), folded into q at projection time
#define SCK 0.25506974748975505f

// ---------------------------------------------------------------------------
// Weight prep: Wo->Wt[tap][o][c] bf16 ; Wq,Wk->Wqk[64][256] ; Wv->Wvb bf16
// ---------------------------------------------------------------------------
__global__ __launch_bounds__(256) void w_prep_kernel(
    const float* __restrict__ Wo, const float* __restrict__ Wq,
    const float* __restrict__ Wk, const float* __restrict__ Wv,
    __hip_bfloat16* __restrict__ Wt, __hip_bfloat16* __restrict__ Wqk,
    __hip_bfloat16* __restrict__ Wvb)
{
    int blk = blockIdx.x, t = threadIdx.x;
    if (blk < 256) {
        const float* src = &Wo[(size_t)(blk * 256 + t) * 9];
#pragma unroll
        for (int tap = 0; tap < 9; ++tap)
            Wt[(size_t)(tap * 256 + blk) * 256 + t] = __float2bfloat16(src[tap]);
    } else if (blk < 260) {
        int r0 = (blk - 256) * 64;
        for (int r = r0; r < r0 + 64; ++r)
            Wvb[r * 256 + t] = __float2bfloat16(Wv[r * 256 + t]);
    } else {
        for (int r = 0; r < 32; ++r) {
            // q rows pre-scaled by SCK (softmax scale * log2e folded in)
            Wqk[r * 256 + t]        = __float2bfloat16(Wq[r * 256 + t] * SCK);
            Wqk[(r + 32) * 256 + t] = __float2bfloat16(Wk[r * 256 + t]);
        }
    }
}

// ---------------------------------------------------------------------------
// Fused QKV projection v3 (r19): block = 16 n, grid B*256 = 1024.
// ---------------------------------------------------------------------------
__global__ __launch_bounds__(256) void qkv_kernel(
    const float* __restrict__ x,
    const __hip_bfloat16* __restrict__ Wqk, const __hip_bfloat16* __restrict__ Wvb,
    const float* __restrict__ bq, const float* __restrict__ bk,
    const float* __restrict__ bv,
    __hip_bfloat16* __restrict__ qg, __hip_bfloat16* __restrict__ kg,
    __hip_bfloat16* __restrict__ vg)
{
    __shared__ __hip_bfloat16 tl[16][72];   // [n][c-chunk] pad 8
    int blk = blockIdx.x;
    int b = blk >> 8, n0 = (blk & 255) * 16;
    int t = threadIdx.x, w = t >> 6, lane = t & 63;
    int l15 = lane & 15, l4 = lane >> 4;
    int n = n0 + l15;

    // wave's 5 A-row base pointers (tiles w*5 .. w*5+4)
    const __hip_bfloat16* wrow[5];
#pragma unroll
    for (int mi = 0; mi < 5; ++mi) {
        int ti = w * 5 + mi;
        wrow[mi] = (ti < 4) ? &Wqk[(size_t)(ti * 16 + l15) * 256]
                            : &Wvb[(size_t)((ti - 4) * 16 + l15) * 256];
    }

    f32x4 zf = {0.f, 0.f, 0.f, 0.f};
    f32x4 acc[5];
#pragma unroll
    for (int m = 0; m < 5; ++m) acc[m] = zf;

    for (int cc = 0; cc < 256; cc += 64) {
        __syncthreads();
        {   // stage 64c x 16n transposed -> tl (1 float4/thread)
            int c = t >> 2, n4 = (t & 3) * 4;
            float4 v4 = *(const float4*)&x[((size_t)(b * 256 + cc + c)) * N_TOK + n0 + n4];
            tl[n4 + 0][c] = __float2bfloat16(v4.x);
            tl[n4 + 1][c] = __float2bfloat16(v4.y);
            tl[n4 + 2][c] = __float2bfloat16(v4.z);
            tl[n4 + 3][c] = __float2bfloat16(v4.w);
        }
        __syncthreads();
#pragma unroll
        for (int kk = 0; kk < 2; ++kk) {
            short8 bfr = *(const short8*)&tl[l15][kk * 32 + l4 * 8];
#pragma unroll
            for (int mi = 0; mi < 5; ++mi) {
                short8 af = *(const short8*)&wrow[mi][cc + kk * 32 + l4 * 8];
                acc[mi] = MFMA16(af, bfr, acc[mi]);
            }
        }
    }

    // epilogue (wave-uniform branches per tile)
#pragma unroll
    for (int mi = 0; mi < 5; ++mi) {
        int ti = w * 5 + mi;
        if (ti < 2) {            // q tiles: bias*SCK, (B,N,32)
            int oofs = ti * 16 + l4 * 4;
            f32x4 bb = *(const f32x4*)&bq[oofs];
            uint2 u;
            u.x = pack_bf16x2(acc[mi][0] + bb[0] * SCK, acc[mi][1] + bb[1] * SCK);
            u.y = pack_bf16x2(acc[mi][2] + bb[2] * SCK, acc[mi][3] + bb[3] * SCK);
            *(uint2*)&qg[((size_t)(b * N_TOK + n)) * 32 + oofs] = u;
        } else if (ti < 4) {     // k tiles
            int oofs = (ti - 2) * 16 + l4 * 4;
            f32x4 bb = *(const f32x4*)&bk[oofs];
            uint2 u;
            u.x = pack_bf16x2(acc[mi][0] + bb[0], acc[mi][1] + bb[1]);
            u.y = pack_bf16x2(acc[mi][2] + bb[2], acc[mi][3] + bb[3]);
            *(uint2*)&kg[((size_t)(b * N_TOK + n)) * 32 + oofs] = u;
        } else {                 // v tiles: (B,C,N)
            int cb = (ti - 4) * 16 + l4 * 4;
            f32x4 bvv = *(const f32x4*)&bv[cb];
#pragma unroll
            for (int r = 0; r < 4; ++r)
                vg[((size_t)(b * 256 + cb + r)) * N_TOK + n] = __float2bfloat16(acc[mi][r] + bvv[r]);
        }
    }
}

// ---------------------------------------------------------------------------
// Flash v8 (r13-proven, byte-identical): kh=2 key-split, wave = 32q x 128c,
// block = 4 waves, grid = 512 (2 blocks/CU). K staged in LDS (swz4), V dbuf,
// wave-private P. Bare-exp2 softmax, unnormalized partials + L.
// FROZEN: kh=3 (r12,r16) and unroll-2 (r14) all regressed. Do not perturb.
// ---------------------------------------------------------------------------
__global__ __launch_bounds__(256, 2) void flash_kernel(
    const __hip_bfloat16* __restrict__ qg, const __hip_bfloat16* __restrict__ kg,
    const __hip_bfloat16* __restrict__ vg,
    __hip_bfloat16* __restrict__ ph0, __hip_bfloat16* __restrict__ ph1,
    float* __restrict__ Lh)
{
    __shared__ __hip_bfloat16 v_lds[2][128 * 64];  // 32 KB [c][64k]
    __shared__ __hip_bfloat16 k_lds[2][64 * 32];   // 8 KB [key][32d]
    __shared__ __hip_bfloat16 p_lds[4][32 * 64];   // 16 KB wave-private [q][64k]

    int blk = blockIdx.x;
    int work = (blk & 7) * 64 + (blk >> 3);
    int g = work >> 6;
    int kh = g >> 2, cs = (g >> 1) & 1, bl = g & 1;
    int rem = work & 63;
    int b = ((rem >> 5) << 1) | bl;
    int qgp = rem & 31;
    int t = threadIdx.x, w = t >> 6, lane = t & 63;
    int l15 = lane & 15, l4 = lane >> 4;
    int qw = qgp * 128 + w * 32;

    short8 qf[2];
#pragma unroll
    for (int qs = 0; qs < 2; ++qs)
        qf[qs] = *(const short8*)&qg[((size_t)(b * N_TOK + qw + qs * 16 + l15)) * 32 + l4 * 8];

    f32x4 zf = {0.f, 0.f, 0.f, 0.f};
    f32x4 acc[2][8];
#pragma unroll
    for (int qs = 0; qs < 2; ++qs)
#pragma unroll
        for (int ct = 0; ct < 8; ++ct) acc[qs][ct] = zf;
    float Lr[2] = {0.f, 0.f};

    int vc  = t >> 1;
    int kb4 = (t & 1) * 4;
    int kr  = t >> 2;
    int kch = t & 3;

    const __hip_bfloat16* vrow  = &vg[((size_t)(b * 256 + cs * 128 + vc)) * N_TOK + kh * 2048];
    const __hip_bfloat16* kbase = &kg[((size_t)(b * N_TOK + kh * 2048)) * 32];

    uint4 vp[4], kp;

#pragma unroll
    for (int j = 0; j < 4; ++j)
        vp[j] = *(const uint4*)&vrow[(kb4 + j) * 8];
    kp = *(const uint4*)&kbase[kr * 32 + kch * 8];
#pragma unroll
    for (int j = 0; j < 4; ++j)
        *(uint4*)&v_lds[0][vc * 64 + (((2 * (kb4 + j)) ^ (vc & 14)) << 2)] = vp[j];
    *(uint4*)&k_lds[0][kr * 32 + swz4(kch, kr) * 8] = kp;
    __syncthreads();

    int buf = 0;
    for (int it = 0; it < 32; ++it) {
        int nm0 = it * 64 + 64;
        bool more = (it < 31);
        if (more) {
#pragma unroll
            for (int j = 0; j < 4; ++j)
                vp[j] = *(const uint4*)&vrow[nm0 + (kb4 + j) * 8];
            kp = *(const uint4*)&kbase[(size_t)(nm0 + kr) * 32 + kch * 8];
        }

        short8 kf[4];
#pragma unroll
        for (int kt = 0; kt < 4; ++kt) {
            int row = kt * 16 + l15;
            kf[kt] = *(const short8*)&k_lds[buf][row * 32 + swz4(l4, row) * 8];
        }
        f32x4 sf[2][4];
#pragma unroll
        for (int qs = 0; qs < 2; ++qs)
#pragma unroll
            for (int kt = 0; kt < 4; ++kt)
                sf[qs][kt] = MFMA16(kf[kt], qf[qs], zf);

        // ---- bare exp2 (scale folded into q; no shift needed)
#pragma unroll
        for (int qs = 0; qs < 2; ++qs) {
            int prow = qs * 16 + l15;
#pragma unroll
            for (int kt = 0; kt < 4; ++kt) {
                float p0 = exp2f(sf[qs][kt][0]);
                float p1 = exp2f(sf[qs][kt][1]);
                float p2 = exp2f(sf[qs][kt][2]);
                float p3 = exp2f(sf[qs][kt][3]);
                Lr[qs] += (p0 + p1) + (p2 + p3);
                uint2 u;
                u.x = pack_bf16x2(p0, p1);
                u.y = pack_bf16x2(p2, p3);
                *(uint2*)&p_lds[w][prow * 64 + (((kt * 4 + l4) ^ (l15 & 14)) << 2)] = u;
            }
        }

#pragma unroll
        for (int ks = 0; ks < 2; ++ks) {
            short8 pb[2];
#pragma unroll
            for (int qs = 0; qs < 2; ++qs)
                pb[qs] = *(const short8*)&p_lds[w][(qs * 16 + l15) * 64 +
                         (((ks * 8 + l4 * 2) ^ (l15 & 14)) << 2)];
#pragma unroll
            for (int ct = 0; ct < 8; ++ct) {
                int cr = ct * 16 + l15;
                short8 vf = *(const short8*)&v_lds[buf][cr * 64 +
                           (((ks * 8 + l4 * 2) ^ (cr & 14)) << 2)];
                acc[0][ct] = MFMA16(vf, pb[0], acc[0][ct]);
                acc[1][ct] = MFMA16(vf, pb[1], acc[1][ct]);
            }
        }

        if (more) {
#pragma unroll
            for (int j = 0; j < 4; ++j)
                *(uint4*)&v_lds[buf ^ 1][vc * 64 + (((2 * (kb4 + j)) ^ (vc & 14)) << 2)] = vp[j];
            *(uint4*)&k_lds[buf ^ 1][kr * 32 + swz4(kch, kr) * 8] = kp;
            buf ^= 1;
        }
        __syncthreads();
    }

#pragma unroll
    for (int qs = 0; qs < 2; ++qs) {
        float L = Lr[qs];
        L += __shfl_xor(L, 16);
        L += __shfl_xor(L, 32);
        int nq = qw + qs * 16 + l15;
        if (cs == 0 && l4 == 0)
            Lh[kh * 16384 + b * 4096 + nq] = L;
        __hip_bfloat16* pdst = kh ? ph1 : ph0;
        size_t pix = (size_t)(b * N_TOK + nq);
#pragma unroll
        for (int ct = 0; ct < 8; ++ct) {
            int cl = cs * 128 + ct * 16 + l4 * 4;
            uint2 u;
            u.x = pack_bf16x2(acc[qs][ct][0], acc[qs][ct][1]);
            u.y = pack_bf16x2(acc[qs][ct][2], acc[qs][ct][3]);
            *(uint2*)&pdst[pix * 256 + cl] = u;
        }
    }
}

// ---------------------------------------------------------------------------
// Combine (r8-proven): att = (ph0 + ph1) / (L0 + L1). att aliases ph1.
// ---------------------------------------------------------------------------
__global__ __launch_bounds__(256) void combine_kernel(
    const __hip_bfloat16* __restrict__ ph0, const __hip_bfloat16* __restrict__ ph1,
    const float* __restrict__ Lh, __hip_bfloat16* __restrict__ att)
{
    int idx = blockIdx.x * 256 + threadIdx.x;   // 524288 threads, 8 ch each
    size_t e = (size_t)idx * 8;
    int bn = (int)(e >> 8);
    float inv = 1.f / (Lh[bn] + Lh[16384 + bn]);
    uint4 a = *(const uint4*)&ph0[e];
    uint4 b4 = *(const uint4*)&ph1[e];
    const unsigned* ap = (const unsigned*)&a;
    const unsigned* bp = (const unsigned*)&b4;
    uint4 o;
    unsigned* op = (unsigned*)&o;
#pragma unroll
    for (int j = 0; j < 4; ++j) {
        float lo = (bf2f((unsigned short)(ap[j] & 0xffff)) +
                    bf2f((unsigned short)(bp[j] & 0xffff))) * inv;
        float hi = (bf2f((unsigned short)(ap[j] >> 16)) +
                    bf2f((unsigned short)(bp[j] >> 16))) * inv;
        op[j] = pack_bf16x2(lo, hi);
    }
    *(uint4*)&att[e] = o;
}

// ---------------------------------------------------------------------------
// Implicit-GEMM 3x3 conv via MFMA + bias + BN + ReLU + residual.
// v5: o32, spatial 16x8, grid 1024 — with XCD-aware work remap: XCD x owns
// group g = (b, ob-half) so its att working set (one batch image, ~2.5 MB)
// and Wt slice (0.58 MB) are L2-resident across the 4 ob x 32 sp re-reads.
// ---------------------------------------------------------------------------
__global__ __launch_bounds__(256) void conv_mfma_kernel(
    const __hip_bfloat16* __restrict__ att, const __hip_bfloat16* __restrict__ Wt,
    const float* __restrict__ bo,  const float* __restrict__ gamma,
    const float* __restrict__ beta, const float* __restrict__ mean,
    const float* __restrict__ var, const float* __restrict__ x,
    float* __restrict__ out)
{
    __shared__ __hip_bfloat16 in_lds[180 * 32];     // [10x18 halo][32c] swz
    __shared__ __hip_bfloat16 wt_lds[9 * 32 * 32];  // [tap][o32][32c] swz

    int blk = blockIdx.x;
    // XCD-bijective remap: 1024 = 8 XCDs x 128 works
    int work = (blk & 7) * 128 + (blk >> 3);
    int g = work >> 7;                // 0..7 = (b, ob-half)
    int b = g >> 1, obh = g & 1;
    int rem = work & 127;
    int ob = obh * 4 + (rem >> 5);    // 0..7
    int sp = rem & 31;
    int y0 = (sp >> 2) * 8, x0 = (sp & 3) * 16;
    int o0 = ob * 32;
    int t = threadIdx.x;
    int w = t >> 6, lane = t & 63;
    int l15 = lane & 15, l4 = lane >> 4;

    f32x4 zf = {0.f, 0.f, 0.f, 0.f};
    f32x4 acc[2][2];   // [m][ntw]
#pragma unroll
    for (int m = 0; m < 2; ++m)
#pragma unroll
        for (int n = 0; n < 2; ++n) acc[m][n] = zf;

    for (int cc = 0; cc < 256; cc += 32) {
        __syncthreads();
        for (int jj = t; jj < 720; jj += 256) {
            int pix = jj >> 2, h = jj & 3;
            int iy = pix / 18, ix = pix - iy * 18;
            int gy = y0 - 1 + iy, gx = x0 - 1 + ix;
            uint4 val = {0u, 0u, 0u, 0u};
            if (gy >= 0 && gy < 64 && gx >= 0 && gx < 64)
                val = *(const uint4*)&att[((size_t)(b * 4096 + gy * 64 + gx)) * 256 + cc + h * 8];
            *(uint4*)&in_lds[pix * 32 + swz4(h, pix) * 8] = val;
        }
        for (int jj = t; jj < 1152; jj += 256) {
            int tap = jj >> 7, rem2 = jj & 127;
            int o = rem2 >> 2, h = rem2 & 3;
            uint4 wv = *(const uint4*)&Wt[((size_t)(tap * 256 + o0 + o)) * 256 + cc + h * 8];
            *(uint4*)&wt_lds[tap * 1024 + o * 32 + swz4(h, o) * 8] = wv;
        }
        __syncthreads();

#pragma unroll
        for (int ky = 0; ky < 3; ++ky) {
#pragma unroll
            for (int kx = 0; kx < 3; ++kx) {
                int tap = ky * 3 + kx;
                short8 af[2];
#pragma unroll
                for (int m = 0; m < 2; ++m) {
                    int orow = m * 16 + l15;
                    af[m] = *(const short8*)&wt_lds[tap * 1024 + orow * 32 + swz4(l4, orow) * 8];
                }
#pragma unroll
                for (int ntw = 0; ntw < 2; ++ntw) {
                    int yy = w * 2 + ntw;
                    int p = (yy + ky) * 18 + kx + l15;
                    short8 bfr = *(const short8*)&in_lds[p * 32 + swz4(l4, p) * 8];
#pragma unroll
                    for (int m = 0; m < 2; ++m)
                        acc[m][ntw] = MFMA16(af[m], bfr, acc[m][ntw]);
                }
            }
        }
    }

#pragma unroll
    for (int m = 0; m < 2; ++m) {
#pragma unroll
        for (int r = 0; r < 4; ++r) {
            int oc = o0 + m * 16 + l4 * 4 + r;
            float inv = gamma[oc] * rsqrtf(var[oc] + 1e-5f);
            float sh  = (bo[oc] - mean[oc]) * inv + beta[oc];
#pragma unroll
            for (int ntw = 0; ntw < 2; ++ntw) {
                int gy = y0 + w * 2 + ntw, gx = x0 + l15;
                size_t idx = (size_t)(b * 256 + oc) * 4096 + (size_t)gy * 64 + gx;
                float yv = acc[m][ntw][r] * inv + sh;
                yv = fmaxf(yv, 0.f);
                out[idx] = yv + x[idx];
            }
        }
    }
}

// ---------------------------------------------------------------------------
extern "C" void kernel_launch(void* const* d_in, const int* in_sizes, int n_in,
                              void* d_out, int out_size, void* d_ws, size_t ws_size,
                              hipStream_t stream)
{
    const float* x  = (const float*)d_in[0];
    const float* Wq = (const float*)d_in[1];
    const float* bq = (const float*)d_in[2];
    const float* Wk = (const float*)d_in[3];
    const float* bk = (const float*)d_in[4];
    const float* Wv = (const float*)d_in[5];
    const float* bv = (const float*)d_in[6];
    const float* Wo = (const float*)d_in[7];
    const float* bo = (const float*)d_in[8];
    const float* gm = (const float*)d_in[9];
    const float* bt = (const float*)d_in[10];
    const float* mn = (const float*)d_in[11];
    const float* vr = (const float*)d_in[12];
    float* out = (float*)d_out;

    char* wsb = (char*)d_ws;
    __hip_bfloat16* qg  = (__hip_bfloat16*)(wsb);                      // 1 MB
    __hip_bfloat16* kg  = (__hip_bfloat16*)(wsb + (1u  << 20));        // 1 MB
    __hip_bfloat16* vg  = (__hip_bfloat16*)(wsb + (2u  << 20));        // 8 MB
    __hip_bfloat16* ph1 = (__hip_bfloat16*)(wsb + (10u << 20));        // 8 MB (= att)
    __hip_bfloat16* Wt  = (__hip_bfloat16*)(wsb + (18u << 20));        // 1.2 MB
    __hip_bfloat16* ph0 = (__hip_bfloat16*)(wsb + (20u << 20));        // 8 MB
    __hip_bfloat16* Wqk = (__hip_bfloat16*)(wsb + (28u << 20));        // 32 KB
    __hip_bfloat16* Wvb = (__hip_bfloat16*)(wsb + (28u << 20) + 65536);// 128 KB
    float*          Lh  = (float*)(wsb + (28u << 20) + 262144);        // 128 KB

    __hip_bfloat16* att = ph1;  // combine writes in place (elementwise)

    w_prep_kernel  <<<261,  256, 0, stream>>>(Wo, Wq, Wk, Wv, Wt, Wqk, Wvb);
    qkv_kernel     <<<1024, 256, 0, stream>>>(x, Wqk, Wvb, bq, bk, bv, qg, kg, vg);
    flash_kernel   <<<512,  256, 0, stream>>>(qg, kg, vg, ph0, ph1, Lh);
    combine_kernel <<<2048, 256, 0, stream>>>(ph0, ph1, Lh, att);
    conv_mfma_kernel<<<1024, 256, 0, stream>>>(att, Wt, bo, gm, bt, mn, vr, x, out);
}

// Round 21
// 138.394 us; speedup vs baseline: 1.2638x; 1.0048x over previous
//
#include <hip/hip_runtime.h>
#include <hip/hip_bf16.h>
#include <math.h>

#define N_TOK 4096

typedef __attribute__((ext_vector_type(8))) short short8;
typedef __attribute__((ext_vector_type(4))) float f32x4;

#define MFMA16(a, b, c) __builtin_amdgcn_mfma_f32_16x16x32_bf16(a, b, c, 0, 0, 0)

__device__ inline unsigned pack_bf16x2(float a, float b) {
    __hip_bfloat16 ha = __float2bfloat16(a), hb = __float2bfloat16(b);
    unsigned short ua = *(unsigned short*)&ha, ub = *(unsigned short*)&hb;
    return (unsigned)ua | ((unsigned)ub << 16);
}

__device__ inline float bf2f(unsigned short u) {
    unsigned v = ((unsigned)u) << 16;
    union { unsigned u; float f; } cv; cv.u = v; return cv.f;
}

// swizzled 16B-chunk slot for row-stride-64B LDS tiles (<=2-way conflicts)
__device__ inline int swz4(int h, int row) { return (h ^ row ^ (row >> 2)) & 3; }

// scale * log2(e), folded into q at projection time
#define SCK 0.25506974748975505f

// ---------------------------------------------------------------------------
// Weight prep: Wo->Wt[tap][o][c] bf16 ; Wq,Wk->Wqk[64][256] ; Wv->Wvb bf16
// ---------------------------------------------------------------------------
__global__ __launch_bounds__(256) void w_prep_kernel(
    const float* __restrict__ Wo, const float* __restrict__ Wq,
    const float* __restrict__ Wk, const float* __restrict__ Wv,
    __hip_bfloat16* __restrict__ Wt, __hip_bfloat16* __restrict__ Wqk,
    __hip_bfloat16* __restrict__ Wvb)
{
    int blk = blockIdx.x, t = threadIdx.x;
    if (blk < 256) {
        const float* src = &Wo[(size_t)(blk * 256 + t) * 9];
#pragma unroll
        for (int tap = 0; tap < 9; ++tap)
            Wt[(size_t)(tap * 256 + blk) * 256 + t] = __float2bfloat16(src[tap]);
    } else if (blk < 260) {
        int r0 = (blk - 256) * 64;
        for (int r = r0; r < r0 + 64; ++r)
            Wvb[r * 256 + t] = __float2bfloat16(Wv[r * 256 + t]);
    } else {
        for (int r = 0; r < 32; ++r) {
            // q rows pre-scaled by SCK (softmax scale * log2e folded in)
            Wqk[r * 256 + t]        = __float2bfloat16(Wq[r * 256 + t] * SCK);
            Wqk[(r + 32) * 256 + t] = __float2bfloat16(Wk[r * 256 + t]);
        }
    }
}

// ---------------------------------------------------------------------------
// Fused QKV projection v3 (r19): block = 16 n, grid B*256 = 1024.
// ---------------------------------------------------------------------------
__global__ __launch_bounds__(256) void qkv_kernel(
    const float* __restrict__ x,
    const __hip_bfloat16* __restrict__ Wqk, const __hip_bfloat16* __restrict__ Wvb,
    const float* __restrict__ bq, const float* __restrict__ bk,
    const float* __restrict__ bv,
    __hip_bfloat16* __restrict__ qg, __hip_bfloat16* __restrict__ kg,
    __hip_bfloat16* __restrict__ vg)
{
    __shared__ __hip_bfloat16 tl[16][72];   // [n][c-chunk] pad 8
    int blk = blockIdx.x;
    int b = blk >> 8, n0 = (blk & 255) * 16;
    int t = threadIdx.x, w = t >> 6, lane = t & 63;
    int l15 = lane & 15, l4 = lane >> 4;
    int n = n0 + l15;

    // wave's 5 A-row base pointers (tiles w*5 .. w*5+4)
    const __hip_bfloat16* wrow[5];
#pragma unroll
    for (int mi = 0; mi < 5; ++mi) {
        int ti = w * 5 + mi;
        wrow[mi] = (ti < 4) ? &Wqk[(size_t)(ti * 16 + l15) * 256]
                            : &Wvb[(size_t)((ti - 4) * 16 + l15) * 256];
    }

    f32x4 zf = {0.f, 0.f, 0.f, 0.f};
    f32x4 acc[5];
#pragma unroll
    for (int m = 0; m < 5; ++m) acc[m] = zf;

    for (int cc = 0; cc < 256; cc += 64) {
        __syncthreads();
        {   // stage 64c x 16n transposed -> tl (1 float4/thread)
            int c = t >> 2, n4 = (t & 3) * 4;
            float4 v4 = *(const float4*)&x[((size_t)(b * 256 + cc + c)) * N_TOK + n0 + n4];
            tl[n4 + 0][c] = __float2bfloat16(v4.x);
            tl[n4 + 1][c] = __float2bfloat16(v4.y);
            tl[n4 + 2][c] = __float2bfloat16(v4.z);
            tl[n4 + 3][c] = __float2bfloat16(v4.w);
        }
        __syncthreads();
#pragma unroll
        for (int kk = 0; kk < 2; ++kk) {
            short8 bfr = *(const short8*)&tl[l15][kk * 32 + l4 * 8];
#pragma unroll
            for (int mi = 0; mi < 5; ++mi) {
                short8 af = *(const short8*)&wrow[mi][cc + kk * 32 + l4 * 8];
                acc[mi] = MFMA16(af, bfr, acc[mi]);
            }
        }
    }

    // epilogue (wave-uniform branches per tile)
#pragma unroll
    for (int mi = 0; mi < 5; ++mi) {
        int ti = w * 5 + mi;
        if (ti < 2) {            // q tiles: bias*SCK, (B,N,32)
            int oofs = ti * 16 + l4 * 4;
            f32x4 bb = *(const f32x4*)&bq[oofs];
            uint2 u;
            u.x = pack_bf16x2(acc[mi][0] + bb[0] * SCK, acc[mi][1] + bb[1] * SCK);
            u.y = pack_bf16x2(acc[mi][2] + bb[2] * SCK, acc[mi][3] + bb[3] * SCK);
            *(uint2*)&qg[((size_t)(b * N_TOK + n)) * 32 + oofs] = u;
        } else if (ti < 4) {     // k tiles
            int oofs = (ti - 2) * 16 + l4 * 4;
            f32x4 bb = *(const f32x4*)&bk[oofs];
            uint2 u;
            u.x = pack_bf16x2(acc[mi][0] + bb[0], acc[mi][1] + bb[1]);
            u.y = pack_bf16x2(acc[mi][2] + bb[2], acc[mi][3] + bb[3]);
            *(uint2*)&kg[((size_t)(b * N_TOK + n)) * 32 + oofs] = u;
        } else {                 // v tiles: (B,C,N)
            int cb = (ti - 4) * 16 + l4 * 4;
            f32x4 bvv = *(const f32x4*)&bv[cb];
#pragma unroll
            for (int r = 0; r < 4; ++r)
                vg[((size_t)(b * 256 + cb + r)) * N_TOK + n] = __float2bfloat16(acc[mi][r] + bvv[r]);
        }
    }
}

// ---------------------------------------------------------------------------
// Flash v8 + T5 setprio: structure byte-identical to r13/r20 (FROZEN); only
// addition is s_setprio(1)/(0) around the S-MFMA and PV-MFMA clusters —
// regime-matched per catalog (attn, independent blocks/CU: +4-7%; zero
// correctness risk, pure scheduler hint).
// ---------------------------------------------------------------------------
__global__ __launch_bounds__(256, 2) void flash_kernel(
    const __hip_bfloat16* __restrict__ qg, const __hip_bfloat16* __restrict__ kg,
    const __hip_bfloat16* __restrict__ vg,
    __hip_bfloat16* __restrict__ ph0, __hip_bfloat16* __restrict__ ph1,
    float* __restrict__ Lh)
{
    __shared__ __hip_bfloat16 v_lds[2][128 * 64];  // 32 KB [c][64k]
    __shared__ __hip_bfloat16 k_lds[2][64 * 32];   // 8 KB [key][32d]
    __shared__ __hip_bfloat16 p_lds[4][32 * 64];   // 16 KB wave-private [q][64k]

    int blk = blockIdx.x;
    int work = (blk & 7) * 64 + (blk >> 3);
    int g = work >> 6;
    int kh = g >> 2, cs = (g >> 1) & 1, bl = g & 1;
    int rem = work & 63;
    int b = ((rem >> 5) << 1) | bl;
    int qgp = rem & 31;
    int t = threadIdx.x, w = t >> 6, lane = t & 63;
    int l15 = lane & 15, l4 = lane >> 4;
    int qw = qgp * 128 + w * 32;

    short8 qf[2];
#pragma unroll
    for (int qs = 0; qs < 2; ++qs)
        qf[qs] = *(const short8*)&qg[((size_t)(b * N_TOK + qw + qs * 16 + l15)) * 32 + l4 * 8];

    f32x4 zf = {0.f, 0.f, 0.f, 0.f};
    f32x4 acc[2][8];
#pragma unroll
    for (int qs = 0; qs < 2; ++qs)
#pragma unroll
        for (int ct = 0; ct < 8; ++ct) acc[qs][ct] = zf;
    float Lr[2] = {0.f, 0.f};

    int vc  = t >> 1;
    int kb4 = (t & 1) * 4;
    int kr  = t >> 2;
    int kch = t & 3;

    const __hip_bfloat16* vrow  = &vg[((size_t)(b * 256 + cs * 128 + vc)) * N_TOK + kh * 2048];
    const __hip_bfloat16* kbase = &kg[((size_t)(b * N_TOK + kh * 2048)) * 32];

    uint4 vp[4], kp;

#pragma unroll
    for (int j = 0; j < 4; ++j)
        vp[j] = *(const uint4*)&vrow[(kb4 + j) * 8];
    kp = *(const uint4*)&kbase[kr * 32 + kch * 8];
#pragma unroll
    for (int j = 0; j < 4; ++j)
        *(uint4*)&v_lds[0][vc * 64 + (((2 * (kb4 + j)) ^ (vc & 14)) << 2)] = vp[j];
    *(uint4*)&k_lds[0][kr * 32 + swz4(kch, kr) * 8] = kp;
    __syncthreads();

    int buf = 0;
    for (int it = 0; it < 32; ++it) {
        int nm0 = it * 64 + 64;
        bool more = (it < 31);
        if (more) {
#pragma unroll
            for (int j = 0; j < 4; ++j)
                vp[j] = *(const uint4*)&vrow[nm0 + (kb4 + j) * 8];
            kp = *(const uint4*)&kbase[(size_t)(nm0 + kr) * 32 + kch * 8];
        }

        short8 kf[4];
#pragma unroll
        for (int kt = 0; kt < 4; ++kt) {
            int row = kt * 16 + l15;
            kf[kt] = *(const short8*)&k_lds[buf][row * 32 + swz4(l4, row) * 8];
        }
        __builtin_amdgcn_s_setprio(1);
        f32x4 sf[2][4];
#pragma unroll
        for (int qs = 0; qs < 2; ++qs)
#pragma unroll
            for (int kt = 0; kt < 4; ++kt)
                sf[qs][kt] = MFMA16(kf[kt], qf[qs], zf);
        __builtin_amdgcn_s_setprio(0);

        // ---- bare exp2 (scale folded into q; no shift needed)
#pragma unroll
        for (int qs = 0; qs < 2; ++qs) {
            int prow = qs * 16 + l15;
#pragma unroll
            for (int kt = 0; kt < 4; ++kt) {
                float p0 = exp2f(sf[qs][kt][0]);
                float p1 = exp2f(sf[qs][kt][1]);
                float p2 = exp2f(sf[qs][kt][2]);
                float p3 = exp2f(sf[qs][kt][3]);
                Lr[qs] += (p0 + p1) + (p2 + p3);
                uint2 u;
                u.x = pack_bf16x2(p0, p1);
                u.y = pack_bf16x2(p2, p3);
                *(uint2*)&p_lds[w][prow * 64 + (((kt * 4 + l4) ^ (l15 & 14)) << 2)] = u;
            }
        }

        __builtin_amdgcn_s_setprio(1);
#pragma unroll
        for (int ks = 0; ks < 2; ++ks) {
            short8 pb[2];
#pragma unroll
            for (int qs = 0; qs < 2; ++qs)
                pb[qs] = *(const short8*)&p_lds[w][(qs * 16 + l15) * 64 +
                         (((ks * 8 + l4 * 2) ^ (l15 & 14)) << 2)];
#pragma unroll
            for (int ct = 0; ct < 8; ++ct) {
                int cr = ct * 16 + l15;
                short8 vf = *(const short8*)&v_lds[buf][cr * 64 +
                           (((ks * 8 + l4 * 2) ^ (cr & 14)) << 2)];
                acc[0][ct] = MFMA16(vf, pb[0], acc[0][ct]);
                acc[1][ct] = MFMA16(vf, pb[1], acc[1][ct]);
            }
        }
        __builtin_amdgcn_s_setprio(0);

        if (more) {
#pragma unroll
            for (int j = 0; j < 4; ++j)
                *(uint4*)&v_lds[buf ^ 1][vc * 64 + (((2 * (kb4 + j)) ^ (vc & 14)) << 2)] = vp[j];
            *(uint4*)&k_lds[buf ^ 1][kr * 32 + swz4(kch, kr) * 8] = kp;
            buf ^= 1;
        }
        __syncthreads();
    }

#pragma unroll
    for (int qs = 0; qs < 2; ++qs) {
        float L = Lr[qs];
        L += __shfl_xor(L, 16);
        L += __shfl_xor(L, 32);
        int nq = qw + qs * 16 + l15;
        if (cs == 0 && l4 == 0)
            Lh[kh * 16384 + b * 4096 + nq] = L;
        __hip_bfloat16* pdst = kh ? ph1 : ph0;
        size_t pix = (size_t)(b * N_TOK + nq);
#pragma unroll
        for (int ct = 0; ct < 8; ++ct) {
            int cl = cs * 128 + ct * 16 + l4 * 4;
            uint2 u;
            u.x = pack_bf16x2(acc[qs][ct][0], acc[qs][ct][1]);
            u.y = pack_bf16x2(acc[qs][ct][2], acc[qs][ct][3]);
            *(uint2*)&pdst[pix * 256 + cl] = u;
        }
    }
}

// ---------------------------------------------------------------------------
// Combine (r8-proven): att = (ph0 + ph1) / (L0 + L1). att aliases ph1.
// ---------------------------------------------------------------------------
__global__ __launch_bounds__(256) void combine_kernel(
    const __hip_bfloat16* __restrict__ ph0, const __hip_bfloat16* __restrict__ ph1,
    const float* __restrict__ Lh, __hip_bfloat16* __restrict__ att)
{
    int idx = blockIdx.x * 256 + threadIdx.x;   // 524288 threads, 8 ch each
    size_t e = (size_t)idx * 8;
    int bn = (int)(e >> 8);
    float inv = 1.f / (Lh[bn] + Lh[16384 + bn]);
    uint4 a = *(const uint4*)&ph0[e];
    uint4 b4 = *(const uint4*)&ph1[e];
    const unsigned* ap = (const unsigned*)&a;
    const unsigned* bp = (const unsigned*)&b4;
    uint4 o;
    unsigned* op = (unsigned*)&o;
#pragma unroll
    for (int j = 0; j < 4; ++j) {
        float lo = (bf2f((unsigned short)(ap[j] & 0xffff)) +
                    bf2f((unsigned short)(bp[j] & 0xffff))) * inv;
        float hi = (bf2f((unsigned short)(ap[j] >> 16)) +
                    bf2f((unsigned short)(bp[j] >> 16))) * inv;
        op[j] = pack_bf16x2(lo, hi);
    }
    *(uint4*)&att[e] = o;
}

// ---------------------------------------------------------------------------
// Implicit-GEMM 3x3 conv via MFMA + bias + BN + ReLU + residual.
// v5 (r20-proven): o32, spatial 16x8, grid 1024, XCD-aware work remap.
// ---------------------------------------------------------------------------
__global__ __launch_bounds__(256) void conv_mfma_kernel(
    const __hip_bfloat16* __restrict__ att, const __hip_bfloat16* __restrict__ Wt,
    const float* __restrict__ bo,  const float* __restrict__ gamma,
    const float* __restrict__ beta, const float* __restrict__ mean,
    const float* __restrict__ var, const float* __restrict__ x,
    float* __restrict__ out)
{
    __shared__ __hip_bfloat16 in_lds[180 * 32];     // [10x18 halo][32c] swz
    __shared__ __hip_bfloat16 wt_lds[9 * 32 * 32];  // [tap][o32][32c] swz

    int blk = blockIdx.x;
    // XCD-bijective remap: 1024 = 8 XCDs x 128 works
    int work = (blk & 7) * 128 + (blk >> 3);
    int g = work >> 7;                // 0..7 = (b, ob-half)
    int b = g >> 1, obh = g & 1;
    int rem = work & 127;
    int ob = obh * 4 + (rem >> 5);    // 0..7
    int sp = rem & 31;
    int y0 = (sp >> 2) * 8, x0 = (sp & 3) * 16;
    int o0 = ob * 32;
    int t = threadIdx.x;
    int w = t >> 6, lane = t & 63;
    int l15 = lane & 15, l4 = lane >> 4;

    f32x4 zf = {0.f, 0.f, 0.f, 0.f};
    f32x4 acc[2][2];   // [m][ntw]
#pragma unroll
    for (int m = 0; m < 2; ++m)
#pragma unroll
        for (int n = 0; n < 2; ++n) acc[m][n] = zf;

    for (int cc = 0; cc < 256; cc += 32) {
        __syncthreads();
        for (int jj = t; jj < 720; jj += 256) {
            int pix = jj >> 2, h = jj & 3;
            int iy = pix / 18, ix = pix - iy * 18;
            int gy = y0 - 1 + iy, gx = x0 - 1 + ix;
            uint4 val = {0u, 0u, 0u, 0u};
            if (gy >= 0 && gy < 64 && gx >= 0 && gx < 64)
                val = *(const uint4*)&att[((size_t)(b * 4096 + gy * 64 + gx)) * 256 + cc + h * 8];
            *(uint4*)&in_lds[pix * 32 + swz4(h, pix) * 8] = val;
        }
        for (int jj = t; jj < 1152; jj += 256) {
            int tap = jj >> 7, rem2 = jj & 127;
            int o = rem2 >> 2, h = rem2 & 3;
            uint4 wv = *(const uint4*)&Wt[((size_t)(tap * 256 + o0 + o)) * 256 + cc + h * 8];
            *(uint4*)&wt_lds[tap * 1024 + o * 32 + swz4(h, o) * 8] = wv;
        }
        __syncthreads();

#pragma unroll
        for (int ky = 0; ky < 3; ++ky) {
#pragma unroll
            for (int kx = 0; kx < 3; ++kx) {
                int tap = ky * 3 + kx;
                short8 af[2];
#pragma unroll
                for (int m = 0; m < 2; ++m) {
                    int orow = m * 16 + l15;
                    af[m] = *(const short8*)&wt_lds[tap * 1024 + orow * 32 + swz4(l4, orow) * 8];
                }
#pragma unroll
                for (int ntw = 0; ntw < 2; ++ntw) {
                    int yy = w * 2 + ntw;
                    int p = (yy + ky) * 18 + kx + l15;
                    short8 bfr = *(const short8*)&in_lds[p * 32 + swz4(l4, p) * 8];
#pragma unroll
                    for (int m = 0; m < 2; ++m)
                        acc[m][ntw] = MFMA16(af[m], bfr, acc[m][ntw]);
                }
            }
        }
    }

#pragma unroll
    for (int m = 0; m < 2; ++m) {
#pragma unroll
        for (int r = 0; r < 4; ++r) {
            int oc = o0 + m * 16 + l4 * 4 + r;
            float inv = gamma[oc] * rsqrtf(var[oc] + 1e-5f);
            float sh  = (bo[oc] - mean[oc]) * inv + beta[oc];
#pragma unroll
            for (int ntw = 0; ntw < 2; ++ntw) {
                int gy = y0 + w * 2 + ntw, gx = x0 + l15;
                size_t idx = (size_t)(b * 256 + oc) * 4096 + (size_t)gy * 64 + gx;
                float yv = acc[m][ntw][r] * inv + sh;
                yv = fmaxf(yv, 0.f);
                out[idx] = yv + x[idx];
            }
        }
    }
}

// ---------------------------------------------------------------------------
extern "C" void kernel_launch(void* const* d_in, const int* in_sizes, int n_in,
                              void* d_out, int out_size, void* d_ws, size_t ws_size,
                              hipStream_t stream)
{
    const float* x  = (const float*)d_in[0];
    const float* Wq = (const float*)d_in[1];
    const float* bq = (const float*)d_in[2];
    const float* Wk = (const float*)d_in[3];
    const float* bk = (const float*)d_in[4];
    const float* Wv = (const float*)d_in[5];
    const float* bv = (const float*)d_in[6];
    const float* Wo = (const float*)d_in[7];
    const float* bo = (const float*)d_in[8];
    const float* gm = (const float*)d_in[9];
    const float* bt = (const float*)d_in[10];
    const float* mn = (const float*)d_in[11];
    const float* vr = (const float*)d_in[12];
    float* out = (float*)d_out;

    char* wsb = (char*)d_ws;
    __hip_bfloat16* qg  = (__hip_bfloat16*)(wsb);                      // 1 MB
    __hip_bfloat16* kg  = (__hip_bfloat16*)(wsb + (1u  << 20));        // 1 MB
    __hip_bfloat16* vg  = (__hip_bfloat16*)(wsb + (2u  << 20));        // 8 MB
    __hip_bfloat16* ph1 = (__hip_bfloat16*)(wsb + (10u << 20));        // 8 MB (= att)
    __hip_bfloat16* Wt  = (__hip_bfloat16*)(wsb + (18u << 20));        // 1.2 MB
    __hip_bfloat16* ph0 = (__hip_bfloat16*)(wsb + (20u << 20));        // 8 MB
    __hip_bfloat16* Wqk = (__hip_bfloat16*)(wsb + (28u << 20));        // 32 KB
    __hip_bfloat16* Wvb = (__hip_bfloat16*)(wsb + (28u << 20) + 65536);// 128 KB
    float*          Lh  = (float*)(wsb + (28u << 20) + 262144);        // 128 KB

    __hip_bfloat16* att = ph1;  // combine writes in place (elementwise)

    w_prep_kernel  <<<261,  256, 0, stream>>>(Wo, Wq, Wk, Wv, Wt, Wqk, Wvb);
    qkv_kernel     <<<1024, 256, 0, stream>>>(x, Wqk, Wvb, bq, bk, bv, qg, kg, vg);
    flash_kernel   <<<512,  256, 0, stream>>>(qg, kg, vg, ph0, ph1, Lh);
    combine_kernel <<<2048, 256, 0, stream>>>(ph0, ph1, Lh, att);
    conv_mfma_kernel<<<1024, 256, 0, stream>>>(att, Wt, bo, gm, bt, mn, vr, x, out);
}